// Round 6
// baseline (1993.403 us; speedup 1.0000x reference)
//
#include <hip/hip_runtime.h>

// ---------------- problem constants ----------------
constexpr int cN     = 20000;
constexpr int cT     = 8;
constexpr int cFIN   = 64;
constexpr int cHEADS = 4;
constexpr int cF     = 32;
constexpr int cHID   = 128;        // cHEADS * cF
constexpr int cE     = 320000;
constexpr int cET    = cE + cN;    // edges + self loops
constexpr float cLEAKY = 0.2f;

// ---------------- CSR build ----------------
__global__ void deg_init_kernel(int* deg) {
    int n = blockIdx.x * blockDim.x + threadIdx.x;
    if (n < cN) deg[n] = 1;   // self loop
}

__global__ void deg_count_kernel(const int* ei, int* deg) {
    int e = blockIdx.x * blockDim.x + threadIdx.x;
    if (e < cE) atomicAdd(&deg[ei[cE + e]], 1);   // dst = edge_index[1][e]
}

// exclusive scan of deg[0..cN) -> offs[0..cN], single block of 256
__global__ void scan_kernel(const int* deg, int* offs) {
    __shared__ int lds[256];
    const int CH = 80;                 // 256*80 = 20480 >= cN
    int tid  = threadIdx.x;
    int base = tid * CH;
    int tot = 0;
    for (int j = 0; j < CH; j++) {
        int idx = base + j;
        if (idx < cN) tot += deg[idx];
    }
    lds[tid] = tot;
    __syncthreads();
    for (int off = 1; off < 256; off <<= 1) {
        int v = (tid >= off) ? lds[tid - off] : 0;
        __syncthreads();
        lds[tid] += v;
        __syncthreads();
    }
    int run = lds[tid] - tot;
    for (int j = 0; j < CH; j++) {
        int idx = base + j;
        if (idx < cN) { offs[idx] = run; run += deg[idx]; }
    }
    if (tid == 255) offs[cN] = lds[255];
}

__global__ void cursor_copy_kernel(const int* offs, int* cur) {
    int n = blockIdx.x * blockDim.x + threadIdx.x;
    if (n < cN) cur[n] = offs[n];
}

__global__ void scatter_kernel(const int* ei, int* cur, int* csr) {
    int e = blockIdx.x * blockDim.x + threadIdx.x;
    if (e >= cET) return;
    int s, d;
    if (e < cE) { s = ei[e]; d = ei[cE + e]; }
    else        { s = e - cE; d = s; }
    int pos = atomicAdd(&cur[d], 1);
    csr[pos] = s;
}

// ---------------- GEMM 1: h[n,c] = sum_k x_t[n,k] * W1[c,k], K=64, A fp32 strided ----------------
// tile: 32 nodes x 128 cols per 256-thread block, micro-tile 4x4
__global__ void gemm1_kernel(const float* A, int lda, const float* W, float* out) {
    __shared__ float As[32][36];
    __shared__ float Bs[32][132];
    int tid = threadIdx.x;
    int n0  = blockIdx.x * 32;
    int tc  = tid & 31;
    int tn  = tid >> 5;
    float acc[4][4] = {};

    for (int k0 = 0; k0 < cFIN; k0 += 32) {
        for (int i = 0; i < 4; i++) {
            int p  = tid + i * 256;
            int nn = p >> 5, kk = p & 31;
            As[kk][nn] = A[(size_t)(n0 + nn) * lda + k0 + kk];
        }
        for (int i = 0; i < 16; i++) {
            int p  = tid + i * 256;
            int c  = p >> 5, kk = p & 31;
            Bs[kk][c] = W[c * cFIN + k0 + kk];
        }
        __syncthreads();
        #pragma unroll
        for (int kk = 0; kk < 32; kk++) {
            float a0 = As[kk][tn * 4 + 0], a1 = As[kk][tn * 4 + 1];
            float a2 = As[kk][tn * 4 + 2], a3 = As[kk][tn * 4 + 3];
            float b0 = Bs[kk][tc * 4 + 0], b1 = Bs[kk][tc * 4 + 1];
            float b2 = Bs[kk][tc * 4 + 2], b3 = Bs[kk][tc * 4 + 3];
            acc[0][0] += a0 * b0; acc[0][1] += a0 * b1; acc[0][2] += a0 * b2; acc[0][3] += a0 * b3;
            acc[1][0] += a1 * b0; acc[1][1] += a1 * b1; acc[1][2] += a1 * b2; acc[1][3] += a1 * b3;
            acc[2][0] += a2 * b0; acc[2][1] += a2 * b1; acc[2][2] += a2 * b2; acc[2][3] += a2 * b3;
            acc[3][0] += a3 * b0; acc[3][1] += a3 * b1; acc[3][2] += a3 * b2; acc[3][3] += a3 * b3;
        }
        __syncthreads();
    }
    for (int i = 0; i < 4; i++)
        for (int j = 0; j < 4; j++)
            out[(size_t)(n0 + tn * 4 + i) * cHID + tc * 4 + j] = acc[i][j];
}

// ---------------- GEMM 2: h[n,c] = sum_k xin[n,k] * W2[c,k], K=128, A fp32 contiguous ----------------
__global__ void gemm2_kernel(const float* A, const float* W, float* out) {
    __shared__ float As[32][36];
    __shared__ float Bs[32][132];
    int tid = threadIdx.x;
    int n0  = blockIdx.x * 32;
    int tc  = tid & 31;
    int tn  = tid >> 5;
    float acc[4][4] = {};

    for (int k0 = 0; k0 < cHID; k0 += 32) {
        for (int i = 0; i < 4; i++) {
            int p  = tid + i * 256;
            int nn = p >> 5, kk = p & 31;
            As[kk][nn] = A[(size_t)(n0 + nn) * cHID + k0 + kk];
        }
        for (int i = 0; i < 16; i++) {
            int p  = tid + i * 256;
            int c  = p >> 5, kk = p & 31;
            Bs[kk][c] = W[c * cHID + k0 + kk];
        }
        __syncthreads();
        #pragma unroll
        for (int kk = 0; kk < 32; kk++) {
            float a0 = As[kk][tn * 4 + 0], a1 = As[kk][tn * 4 + 1];
            float a2 = As[kk][tn * 4 + 2], a3 = As[kk][tn * 4 + 3];
            float b0 = Bs[kk][tc * 4 + 0], b1 = Bs[kk][tc * 4 + 1];
            float b2 = Bs[kk][tc * 4 + 2], b3 = Bs[kk][tc * 4 + 3];
            acc[0][0] += a0 * b0; acc[0][1] += a0 * b1; acc[0][2] += a0 * b2; acc[0][3] += a0 * b3;
            acc[1][0] += a1 * b0; acc[1][1] += a1 * b1; acc[1][2] += a1 * b2; acc[1][3] += a1 * b3;
            acc[2][0] += a2 * b0; acc[2][1] += a2 * b1; acc[2][2] += a2 * b2; acc[2][3] += a2 * b3;
            acc[3][0] += a3 * b0; acc[3][1] += a3 * b1; acc[3][2] += a3 * b2; acc[3][3] += a3 * b3;
        }
        __syncthreads();
    }
    for (int i = 0; i < 4; i++)
        for (int j = 0; j < 4; j++)
            out[(size_t)(n0 + tn * 4 + i) * cHID + tc * 4 + j] = acc[i][j];
}

// ---------------- per-node attention scores ----------------
__global__ void scores_kernel(const float* h, const float* a_src, const float* a_dst,
                              float* es, float* ed) {
    int u = blockIdx.x * blockDim.x + threadIdx.x;
    if (u >= cN * cHEADS) return;
    int n = u >> 2, head = u & 3;
    const float* hp = h + (size_t)n * cHID + head * cF;
    const float* s_ = a_src + head * cF;
    const float* d_ = a_dst + head * cF;
    float s1 = 0.f, s2 = 0.f;
    #pragma unroll 8
    for (int f = 0; f < cF; f++) {
        float hv = hp[f];
        s1 += hv * s_[f];
        s2 += hv * d_[f];
    }
    es[u] = s1;
    ed[u] = s2;
}

// ---------------- pull-based softmax aggregation + bias + ELU ----------------
// one block (128 threads) per dst node; thread j handles feature j (head = j/32)
__global__ void agg_kernel(const float* h, const float* es, const float* ed,
                           const int* offs, const int* csr, const float* bias,
                           float* out) {
    int n = blockIdx.x;
    int j = threadIdx.x;
    int head = j >> 5;
    int s0 = offs[n], s1 = offs[n + 1];
    float edn = ed[n * cHEADS + head];

    float m = -1e30f;
    for (int i = s0; i < s1; i++) {
        int s = csr[i];
        float sc = es[s * cHEADS + head] + edn;
        sc = (sc >= 0.f) ? sc : cLEAKY * sc;
        m = fmaxf(m, sc);
    }
    float denom = 0.f, acc = 0.f;
    for (int i = s0; i < s1; i++) {
        int s = csr[i];
        float sc = es[s * cHEADS + head] + edn;
        sc = (sc >= 0.f) ? sc : cLEAKY * sc;
        float w = __expf(sc - m);
        denom += w;
        acc += w * h[(size_t)s * cHID + j];
    }
    float v = acc / (denom + 1e-16f) + bias[j];
    v = (v > 0.f) ? v : expm1f(v);   // ELU (alpha=1)
    out[(size_t)n * cHID + j] = v;
}

// ---------------- MLP head: relu(x@lw1.T+lb1) @ lw2.T + lb2 -> fp32 out ----------------
// 256 threads = 8 nodes x 32 output-dims
__global__ void TemporalGAT_20005957665499_kernel(const float* x, const float* lw1,
                                                  const float* lb1, const float* lw2,
                                                  const float* lb2, float* out) {
    int tid = threadIdx.x;
    int n = blockIdx.x * 8 + (tid >> 5);
    int j = tid & 31;
    const float* xp = x + (size_t)n * cHID;
    const float* wp = lw1 + (size_t)j * cHID;
    float s = 0.f;
    #pragma unroll 8
    for (int k = 0; k < cHID; k++) s += xp[k] * wp[k];
    s += lb1[j];
    s = fmaxf(s, 0.f);
    float v = s * lw2[j];
    v += __shfl_xor(v, 16);
    v += __shfl_xor(v, 8);
    v += __shfl_xor(v, 4);
    v += __shfl_xor(v, 2);
    v += __shfl_xor(v, 1);
    if (j == 0) out[n] = v + lb2[0];
}

// ---------------- launch ----------------
extern "C" void kernel_launch(void* const* d_in, const int* in_sizes, int n_in,
                              void* d_out, int out_size, void* d_ws, size_t ws_size,
                              hipStream_t stream) {
    const float* x   = (const float*)d_in[0];   // [N,T,64] fp32
    const int*   ei  = (const int*)d_in[1];     // [2,E] int32
    const float* W1  = (const float*)d_in[2];   // [128,64]
    const float* as1 = (const float*)d_in[3];   // [4,32]
    const float* ad1 = (const float*)d_in[4];
    const float* b1  = (const float*)d_in[5];   // [128]
    const float* W2  = (const float*)d_in[6];   // [128,128]
    const float* as2 = (const float*)d_in[7];
    const float* ad2 = (const float*)d_in[8];
    const float* b2  = (const float*)d_in[9];
    const float* lw1 = (const float*)d_in[10];  // [32,128]
    const float* lb1 = (const float*)d_in[11];  // [32]
    const float* lw2 = (const float*)d_in[12];  // [1,32]
    const float* lb2 = (const float*)d_in[13];  // [1]
    float* out = (float*)d_out;                 // [T,N,1] fp32
    (void)in_sizes; (void)n_in; (void)out_size; (void)ws_size;

    // workspace carve, 256B-aligned (~23 MB of 256 MB)
    char* ws = (char*)d_ws;
    size_t o = 0;
    float* h_buf  = (float*)(ws + o); o += (((size_t)cN * cHID * 4)   + 255) & ~(size_t)255;
    float* x_buf  = (float*)(ws + o); o += (((size_t)cN * cHID * 4)   + 255) & ~(size_t)255;
    float* es_buf = (float*)(ws + o); o += (((size_t)cN * cHEADS * 4) + 255) & ~(size_t)255;
    float* ed_buf = (float*)(ws + o); o += (((size_t)cN * cHEADS * 4) + 255) & ~(size_t)255;
    int*   deg    = (int*)(ws + o);   o += (((size_t)cN * 4)          + 255) & ~(size_t)255;
    int*   offs   = (int*)(ws + o);   o += (((size_t)(cN + 1) * 4)    + 255) & ~(size_t)255;
    int*   cursor = (int*)(ws + o);   o += (((size_t)cN * 4)          + 255) & ~(size_t)255;
    int*   csr    = (int*)(ws + o);   o += (((size_t)cET * 4)         + 255) & ~(size_t)255;

    // ---- CSR build (edge_index launch-invariant; rebuilt every call) ----
    deg_init_kernel<<<(cN + 255) / 256, 256, 0, stream>>>(deg);
    deg_count_kernel<<<(cE + 255) / 256, 256, 0, stream>>>(ei, deg);
    scan_kernel<<<1, 256, 0, stream>>>(deg, offs);
    cursor_copy_kernel<<<(cN + 255) / 256, 256, 0, stream>>>(offs, cursor);
    scatter_kernel<<<(cET + 255) / 256, 256, 0, stream>>>(ei, cursor, csr);

    for (int t = 0; t < cT; t++) {
        // layer 1: x[:, t, :] has row stride T*64
        gemm1_kernel<<<cN / 32, 256, 0, stream>>>(x + t * cFIN, cT * cFIN, W1, h_buf);
        scores_kernel<<<(cN * cHEADS + 255) / 256, 256, 0, stream>>>(h_buf, as1, ad1, es_buf, ed_buf);
        agg_kernel<<<cN, 128, 0, stream>>>(h_buf, es_buf, ed_buf, offs, csr, b1, x_buf);
        // layer 2
        gemm2_kernel<<<cN / 32, 256, 0, stream>>>(x_buf, W2, h_buf);
        scores_kernel<<<(cN * cHEADS + 255) / 256, 256, 0, stream>>>(h_buf, as2, ad2, es_buf, ed_buf);
        agg_kernel<<<cN, 128, 0, stream>>>(h_buf, es_buf, ed_buf, offs, csr, b2, x_buf);
        // MLP head -> out[t*N + n]
        TemporalGAT_20005957665499_kernel<<<cN / 8, 256, 0, stream>>>(x_buf, lw1, lb1, lw2, lb2, out + (size_t)t * cN);
    }
}

// Round 7
// 1670.931 us; speedup vs baseline: 1.1930x; 1.1930x over previous
//
#include <hip/hip_runtime.h>

// ---------------- problem constants ----------------
constexpr int cN     = 20000;
constexpr int cT     = 8;
constexpr int cFIN   = 64;
constexpr int cHEADS = 4;
constexpr int cF     = 32;
constexpr int cHID   = 128;        // cHEADS * cF
constexpr int cE     = 320000;
constexpr int cET    = cE + cN;    // edges + self loops
constexpr float cLEAKY = 0.2f;

// ---------------- CSR build ----------------
__global__ void deg_init_kernel(int* deg) {
    int n = blockIdx.x * blockDim.x + threadIdx.x;
    if (n < cN) deg[n] = 1;   // self loop
}

__global__ void deg_count_kernel(const int* ei, int* deg) {
    int e = blockIdx.x * blockDim.x + threadIdx.x;
    if (e < cE) atomicAdd(&deg[ei[cE + e]], 1);   // dst = edge_index[1][e]
}

// exclusive scan of deg[0..cN) -> offs[0..cN], single block of 256
__global__ void scan_kernel(const int* deg, int* offs) {
    __shared__ int lds[256];
    const int CH = 80;                 // 256*80 = 20480 >= cN
    int tid  = threadIdx.x;
    int base = tid * CH;
    int tot = 0;
    for (int j = 0; j < CH; j++) {
        int idx = base + j;
        if (idx < cN) tot += deg[idx];
    }
    lds[tid] = tot;
    __syncthreads();
    for (int off = 1; off < 256; off <<= 1) {
        int v = (tid >= off) ? lds[tid - off] : 0;
        __syncthreads();
        lds[tid] += v;
        __syncthreads();
    }
    int run = lds[tid] - tot;
    for (int j = 0; j < CH; j++) {
        int idx = base + j;
        if (idx < cN) { offs[idx] = run; run += deg[idx]; }
    }
    if (tid == 255) offs[cN] = lds[255];
}

__global__ void cursor_copy_kernel(const int* offs, int* cur) {
    int n = blockIdx.x * blockDim.x + threadIdx.x;
    if (n < cN) cur[n] = offs[n];
}

__global__ void scatter_kernel(const int* ei, int* cur, int* csr) {
    int e = blockIdx.x * blockDim.x + threadIdx.x;
    if (e >= cET) return;
    int s, d;
    if (e < cE) { s = ei[e]; d = ei[cE + e]; }
    else        { s = e - cE; d = s; }
    int pos = atomicAdd(&cur[d], 1);
    csr[pos] = s;
}

// ---------------- GEMM 1: h[n,c] = sum_k x_t[n,k] * W1[c,k], K=64, A fp32 strided ----------------
__global__ void gemm1_kernel(const float* A, int lda, const float* W, float* out) {
    __shared__ float As[32][36];
    __shared__ float Bs[32][132];
    int tid = threadIdx.x;
    int n0  = blockIdx.x * 32;
    int tc  = tid & 31;
    int tn  = tid >> 5;
    float acc[4][4] = {};

    for (int k0 = 0; k0 < cFIN; k0 += 32) {
        for (int i = 0; i < 4; i++) {
            int p  = tid + i * 256;
            int nn = p >> 5, kk = p & 31;
            As[kk][nn] = A[(size_t)(n0 + nn) * lda + k0 + kk];
        }
        for (int i = 0; i < 16; i++) {
            int p  = tid + i * 256;
            int c  = p >> 5, kk = p & 31;
            Bs[kk][c] = W[c * cFIN + k0 + kk];
        }
        __syncthreads();
        #pragma unroll
        for (int kk = 0; kk < 32; kk++) {
            float a0 = As[kk][tn * 4 + 0], a1 = As[kk][tn * 4 + 1];
            float a2 = As[kk][tn * 4 + 2], a3 = As[kk][tn * 4 + 3];
            float b0 = Bs[kk][tc * 4 + 0], b1 = Bs[kk][tc * 4 + 1];
            float b2 = Bs[kk][tc * 4 + 2], b3 = Bs[kk][tc * 4 + 3];
            acc[0][0] += a0 * b0; acc[0][1] += a0 * b1; acc[0][2] += a0 * b2; acc[0][3] += a0 * b3;
            acc[1][0] += a1 * b0; acc[1][1] += a1 * b1; acc[1][2] += a1 * b2; acc[1][3] += a1 * b3;
            acc[2][0] += a2 * b0; acc[2][1] += a2 * b1; acc[2][2] += a2 * b2; acc[2][3] += a2 * b3;
            acc[3][0] += a3 * b0; acc[3][1] += a3 * b1; acc[3][2] += a3 * b2; acc[3][3] += a3 * b3;
        }
        __syncthreads();
    }
    for (int i = 0; i < 4; i++)
        for (int j = 0; j < 4; j++)
            out[(size_t)(n0 + tn * 4 + i) * cHID + tc * 4 + j] = acc[i][j];
}

// ---------------- GEMM 2: h[n,c] = sum_k xin[n,k] * W2[c,k], K=128, A fp32 contiguous ----------------
__global__ void gemm2_kernel(const float* A, const float* W, float* out) {
    __shared__ float As[32][36];
    __shared__ float Bs[32][132];
    int tid = threadIdx.x;
    int n0  = blockIdx.x * 32;
    int tc  = tid & 31;
    int tn  = tid >> 5;
    float acc[4][4] = {};

    for (int k0 = 0; k0 < cHID; k0 += 32) {
        for (int i = 0; i < 4; i++) {
            int p  = tid + i * 256;
            int nn = p >> 5, kk = p & 31;
            As[kk][nn] = A[(size_t)(n0 + nn) * cHID + k0 + kk];
        }
        for (int i = 0; i < 16; i++) {
            int p  = tid + i * 256;
            int c  = p >> 5, kk = p & 31;
            Bs[kk][c] = W[c * cHID + k0 + kk];
        }
        __syncthreads();
        #pragma unroll
        for (int kk = 0; kk < 32; kk++) {
            float a0 = As[kk][tn * 4 + 0], a1 = As[kk][tn * 4 + 1];
            float a2 = As[kk][tn * 4 + 2], a3 = As[kk][tn * 4 + 3];
            float b0 = Bs[kk][tc * 4 + 0], b1 = Bs[kk][tc * 4 + 1];
            float b2 = Bs[kk][tc * 4 + 2], b3 = Bs[kk][tc * 4 + 3];
            acc[0][0] += a0 * b0; acc[0][1] += a0 * b1; acc[0][2] += a0 * b2; acc[0][3] += a0 * b3;
            acc[1][0] += a1 * b0; acc[1][1] += a1 * b1; acc[1][2] += a1 * b2; acc[1][3] += a1 * b3;
            acc[2][0] += a2 * b0; acc[2][1] += a2 * b1; acc[2][2] += a2 * b2; acc[2][3] += a2 * b3;
            acc[3][0] += a3 * b0; acc[3][1] += a3 * b1; acc[3][2] += a3 * b2; acc[3][3] += a3 * b3;
        }
        __syncthreads();
    }
    for (int i = 0; i < 4; i++)
        for (int j = 0; j < 4; j++)
            out[(size_t)(n0 + tn * 4 + i) * cHID + tc * 4 + j] = acc[i][j];
}

// ---------------- per-node attention scores ----------------
__global__ void scores_kernel(const float* h, const float* a_src, const float* a_dst,
                              float* es, float* ed) {
    int u = blockIdx.x * blockDim.x + threadIdx.x;
    if (u >= cN * cHEADS) return;
    int n = u >> 2, head = u & 3;
    const float* hp = h + (size_t)n * cHID + head * cF;
    const float* s_ = a_src + head * cF;
    const float* d_ = a_dst + head * cF;
    float s1 = 0.f, s2 = 0.f;
    #pragma unroll 8
    for (int f = 0; f < cF; f++) {
        float hv = hp[f];
        s1 += hv * s_[f];
        s2 += hv * d_[f];
    }
    es[u] = s1;
    ed[u] = s2;
}

// ---------------- softmax stats prepass: per (node,head) max + 1/denom ----------------
__global__ void stats_kernel(const float* es, const float* ed,
                             const int* offs, const int* csr,
                             float* m_arr, float* inv_arr) {
    int u = blockIdx.x * blockDim.x + threadIdx.x;   // u = n*4 + head
    if (u >= cN * cHEADS) return;
    int n = u >> 2, head = u & 3;
    int s0 = offs[n], s1 = offs[n + 1];
    float edn = ed[u];
    float m = -1e30f;
    for (int i = s0; i < s1; i++) {
        float sc = es[csr[i] * cHEADS + head] + edn;
        sc = (sc >= 0.f) ? sc : cLEAKY * sc;
        m = fmaxf(m, sc);
    }
    float den = 0.f;
    for (int i = s0; i < s1; i++) {
        float sc = es[csr[i] * cHEADS + head] + edn;
        sc = (sc >= 0.f) ? sc : cLEAKY * sc;
        den += __expf(sc - m);
    }
    m_arr[u]   = m;
    inv_arr[u] = 1.f / (den + 1e-16f);
}

// ---------------- single-pass weighted gather + bias + ELU ----------------
// 32 lanes per node (float4 per lane), 8 nodes per 256-thread block
__global__ void agg_kernel(const float* __restrict__ h, const float* __restrict__ es,
                           const float* __restrict__ ed, const float* __restrict__ m_arr,
                           const float* __restrict__ inv_arr,
                           const int* __restrict__ offs, const int* __restrict__ csr,
                           const float* __restrict__ bias, float* __restrict__ out) {
    int n = blockIdx.x * 8 + (threadIdx.x >> 5);
    int j = threadIdx.x & 31;          // feature group: floats 4j..4j+3
    int head = j >> 3;
    int u = n * cHEADS + head;
    int s0 = offs[n], s1 = offs[n + 1];
    float edn = ed[u], m = m_arr[u], inv = inv_arr[u];

    float4 acc = make_float4(0.f, 0.f, 0.f, 0.f);
    int i = s0;
    for (; i + 1 < s1; i += 2) {
        int sa = csr[i], sb = csr[i + 1];
        float4 ha = *(const float4*)(h + (size_t)sa * cHID + 4 * j);
        float4 hb = *(const float4*)(h + (size_t)sb * cHID + 4 * j);
        float ea = es[sa * cHEADS + head] + edn;
        float eb = es[sb * cHEADS + head] + edn;
        ea = (ea >= 0.f) ? ea : cLEAKY * ea;
        eb = (eb >= 0.f) ? eb : cLEAKY * eb;
        float wa = __expf(ea - m) * inv;
        float wb = __expf(eb - m) * inv;
        acc.x += wa * ha.x + wb * hb.x;
        acc.y += wa * ha.y + wb * hb.y;
        acc.z += wa * ha.z + wb * hb.z;
        acc.w += wa * ha.w + wb * hb.w;
    }
    if (i < s1) {
        int sa = csr[i];
        float4 ha = *(const float4*)(h + (size_t)sa * cHID + 4 * j);
        float ea = es[sa * cHEADS + head] + edn;
        ea = (ea >= 0.f) ? ea : cLEAKY * ea;
        float wa = __expf(ea - m) * inv;
        acc.x += wa * ha.x; acc.y += wa * ha.y; acc.z += wa * ha.z; acc.w += wa * ha.w;
    }
    float4 b4 = *(const float4*)(bias + 4 * j);
    float4 r;
    r.x = acc.x + b4.x; r.x = (r.x > 0.f) ? r.x : expm1f(r.x);
    r.y = acc.y + b4.y; r.y = (r.y > 0.f) ? r.y : expm1f(r.y);
    r.z = acc.z + b4.z; r.z = (r.z > 0.f) ? r.z : expm1f(r.z);
    r.w = acc.w + b4.w; r.w = (r.w > 0.f) ? r.w : expm1f(r.w);
    *(float4*)(out + (size_t)n * cHID + 4 * j) = r;
}

// ---------------- MLP head: relu(x@lw1.T+lb1) @ lw2.T + lb2 -> fp32 out ----------------
__global__ void TemporalGAT_20005957665499_kernel(const float* x, const float* lw1,
                                                  const float* lb1, const float* lw2,
                                                  const float* lb2, float* out) {
    int tid = threadIdx.x;
    int n = blockIdx.x * 8 + (tid >> 5);
    int j = tid & 31;
    const float* xp = x + (size_t)n * cHID;
    const float* wp = lw1 + (size_t)j * cHID;
    float s = 0.f;
    #pragma unroll 8
    for (int k = 0; k < cHID; k++) s += xp[k] * wp[k];
    s += lb1[j];
    s = fmaxf(s, 0.f);
    float v = s * lw2[j];
    v += __shfl_xor(v, 16);
    v += __shfl_xor(v, 8);
    v += __shfl_xor(v, 4);
    v += __shfl_xor(v, 2);
    v += __shfl_xor(v, 1);
    if (j == 0) out[n] = v + lb2[0];
}

// ---------------- launch ----------------
extern "C" void kernel_launch(void* const* d_in, const int* in_sizes, int n_in,
                              void* d_out, int out_size, void* d_ws, size_t ws_size,
                              hipStream_t stream) {
    const float* x   = (const float*)d_in[0];   // [N,T,64] fp32
    const int*   ei  = (const int*)d_in[1];     // [2,E] int32
    const float* W1  = (const float*)d_in[2];   // [128,64]
    const float* as1 = (const float*)d_in[3];   // [4,32]
    const float* ad1 = (const float*)d_in[4];
    const float* b1  = (const float*)d_in[5];   // [128]
    const float* W2  = (const float*)d_in[6];   // [128,128]
    const float* as2 = (const float*)d_in[7];
    const float* ad2 = (const float*)d_in[8];
    const float* b2  = (const float*)d_in[9];
    const float* lw1 = (const float*)d_in[10];  // [32,128]
    const float* lb1 = (const float*)d_in[11];  // [32]
    const float* lw2 = (const float*)d_in[12];  // [1,32]
    const float* lb2 = (const float*)d_in[13];  // [1]
    float* out = (float*)d_out;                 // [T,N,1] fp32
    (void)in_sizes; (void)n_in; (void)out_size; (void)ws_size;

    // workspace carve, 256B-aligned (~24 MB of 256 MB)
    char* ws = (char*)d_ws;
    size_t o = 0;
    float* h_buf   = (float*)(ws + o); o += (((size_t)cN * cHID * 4)   + 255) & ~(size_t)255;
    float* x_buf   = (float*)(ws + o); o += (((size_t)cN * cHID * 4)   + 255) & ~(size_t)255;
    float* es_buf  = (float*)(ws + o); o += (((size_t)cN * cHEADS * 4) + 255) & ~(size_t)255;
    float* ed_buf  = (float*)(ws + o); o += (((size_t)cN * cHEADS * 4) + 255) & ~(size_t)255;
    float* m_buf   = (float*)(ws + o); o += (((size_t)cN * cHEADS * 4) + 255) & ~(size_t)255;
    float* inv_buf = (float*)(ws + o); o += (((size_t)cN * cHEADS * 4) + 255) & ~(size_t)255;
    int*   deg     = (int*)(ws + o);   o += (((size_t)cN * 4)          + 255) & ~(size_t)255;
    int*   offs    = (int*)(ws + o);   o += (((size_t)(cN + 1) * 4)    + 255) & ~(size_t)255;
    int*   cursor  = (int*)(ws + o);   o += (((size_t)cN * 4)          + 255) & ~(size_t)255;
    int*   csr     = (int*)(ws + o);   o += (((size_t)cET * 4)         + 255) & ~(size_t)255;

    // ---- CSR build (edge_index launch-invariant; rebuilt every call) ----
    deg_init_kernel<<<(cN + 255) / 256, 256, 0, stream>>>(deg);
    deg_count_kernel<<<(cE + 255) / 256, 256, 0, stream>>>(ei, deg);
    scan_kernel<<<1, 256, 0, stream>>>(deg, offs);
    cursor_copy_kernel<<<(cN + 255) / 256, 256, 0, stream>>>(offs, cursor);
    scatter_kernel<<<(cET + 255) / 256, 256, 0, stream>>>(ei, cursor, csr);

    const int NH_G = (cN * cHEADS + 255) / 256;
    for (int t = 0; t < cT; t++) {
        // layer 1: x[:, t, :] has row stride T*64
        gemm1_kernel<<<cN / 32, 256, 0, stream>>>(x + t * cFIN, cT * cFIN, W1, h_buf);
        scores_kernel<<<NH_G, 256, 0, stream>>>(h_buf, as1, ad1, es_buf, ed_buf);
        stats_kernel<<<NH_G, 256, 0, stream>>>(es_buf, ed_buf, offs, csr, m_buf, inv_buf);
        agg_kernel<<<cN / 8, 256, 0, stream>>>(h_buf, es_buf, ed_buf, m_buf, inv_buf, offs, csr, b1, x_buf);
        // layer 2
        gemm2_kernel<<<cN / 32, 256, 0, stream>>>(x_buf, W2, h_buf);
        scores_kernel<<<NH_G, 256, 0, stream>>>(h_buf, as2, ad2, es_buf, ed_buf);
        stats_kernel<<<NH_G, 256, 0, stream>>>(es_buf, ed_buf, offs, csr, m_buf, inv_buf);
        agg_kernel<<<cN / 8, 256, 0, stream>>>(h_buf, es_buf, ed_buf, m_buf, inv_buf, offs, csr, b2, x_buf);
        // MLP head -> out[t*N + n]
        TemporalGAT_20005957665499_kernel<<<cN / 8, 256, 0, stream>>>(x_buf, lw1, lb1, lw2, lb2, out + (size_t)t * cN);
    }
}

// Round 8
// 1205.458 us; speedup vs baseline: 1.6536x; 1.3861x over previous
//
#include <hip/hip_runtime.h>

// ---------------- problem constants ----------------
constexpr int cN     = 20000;
constexpr int cT     = 8;
constexpr int cFIN   = 64;
constexpr int cHEADS = 4;
constexpr int cF     = 32;
constexpr int cHID   = 128;        // cHEADS * cF
constexpr int cE     = 320000;
constexpr int cET    = cE + cN;    // edges + self loops
constexpr float cLEAKY = 0.2f;

// ---------------- CSR build ----------------
__global__ void deg_init_kernel(int* deg) {
    int n = blockIdx.x * blockDim.x + threadIdx.x;
    if (n < cN) deg[n] = 1;   // self loop
}

__global__ void deg_count_kernel(const int* ei, int* deg) {
    int e = blockIdx.x * blockDim.x + threadIdx.x;
    if (e < cE) atomicAdd(&deg[ei[cE + e]], 1);   // dst = edge_index[1][e]
}

// exclusive scan of deg[0..cN) -> offs[0..cN], single block of 256
__global__ void scan_kernel(const int* deg, int* offs) {
    __shared__ int lds[256];
    const int CH = 80;                 // 256*80 = 20480 >= cN
    int tid  = threadIdx.x;
    int base = tid * CH;
    int tot = 0;
    for (int j = 0; j < CH; j++) {
        int idx = base + j;
        if (idx < cN) tot += deg[idx];
    }
    lds[tid] = tot;
    __syncthreads();
    for (int off = 1; off < 256; off <<= 1) {
        int v = (tid >= off) ? lds[tid - off] : 0;
        __syncthreads();
        lds[tid] += v;
        __syncthreads();
    }
    int run = lds[tid] - tot;
    for (int j = 0; j < CH; j++) {
        int idx = base + j;
        if (idx < cN) { offs[idx] = run; run += deg[idx]; }
    }
    if (tid == 255) offs[cN] = lds[255];
}

__global__ void cursor_copy_kernel(const int* offs, int* cur) {
    int n = blockIdx.x * blockDim.x + threadIdx.x;
    if (n < cN) cur[n] = offs[n];
}

__global__ void scatter_kernel(const int* ei, int* cur, int* csr) {
    int e = blockIdx.x * blockDim.x + threadIdx.x;
    if (e >= cET) return;
    int s, d;
    if (e < cE) { s = ei[e]; d = ei[cE + e]; }
    else        { s = e - cE; d = s; }
    int pos = atomicAdd(&cur[d], 1);
    csr[pos] = s;
}

// ---------------- GEMM 1 + fused scores: h = x_t @ W1.T; es/ed per (node,head) ----------------
// tile: 32 nodes x 128 cols per 256-thread block, micro-tile 4x4
__global__ void gemm1_kernel(const float* A, int lda, const float* W,
                             const float* a_src, const float* a_dst,
                             float* out, float* es, float* ed) {
    __shared__ float As[32][36];
    __shared__ float Bs[32][132];
    int tid = threadIdx.x;
    int n0  = blockIdx.x * 32;
    int tc  = tid & 31;
    int tn  = tid >> 5;
    float acc[4][4] = {};

    for (int k0 = 0; k0 < cFIN; k0 += 32) {
        for (int i = 0; i < 4; i++) {
            int p  = tid + i * 256;
            int nn = p >> 5, kk = p & 31;
            As[kk][nn] = A[(size_t)(n0 + nn) * lda + k0 + kk];
        }
        for (int i = 0; i < 16; i++) {
            int p  = tid + i * 256;
            int c  = p >> 5, kk = p & 31;
            Bs[kk][c] = W[c * cFIN + k0 + kk];
        }
        __syncthreads();
        #pragma unroll
        for (int kk = 0; kk < 32; kk++) {
            float a0 = As[kk][tn * 4 + 0], a1 = As[kk][tn * 4 + 1];
            float a2 = As[kk][tn * 4 + 2], a3 = As[kk][tn * 4 + 3];
            float b0 = Bs[kk][tc * 4 + 0], b1 = Bs[kk][tc * 4 + 1];
            float b2 = Bs[kk][tc * 4 + 2], b3 = Bs[kk][tc * 4 + 3];
            acc[0][0] += a0 * b0; acc[0][1] += a0 * b1; acc[0][2] += a0 * b2; acc[0][3] += a0 * b3;
            acc[1][0] += a1 * b0; acc[1][1] += a1 * b1; acc[1][2] += a1 * b2; acc[1][3] += a1 * b3;
            acc[2][0] += a2 * b0; acc[2][1] += a2 * b1; acc[2][2] += a2 * b2; acc[2][3] += a2 * b3;
            acc[3][0] += a3 * b0; acc[3][1] += a3 * b1; acc[3][2] += a3 * b2; acc[3][3] += a3 * b3;
        }
        __syncthreads();
    }
    float as0 = a_src[tc * 4 + 0], as1v = a_src[tc * 4 + 1], as2v = a_src[tc * 4 + 2], as3 = a_src[tc * 4 + 3];
    float ad0 = a_dst[tc * 4 + 0], ad1v = a_dst[tc * 4 + 1], ad2v = a_dst[tc * 4 + 2], ad3 = a_dst[tc * 4 + 3];
    int head = tc >> 3;
    #pragma unroll
    for (int i = 0; i < 4; i++) {
        int n = n0 + tn * 4 + i;
        float4 v = make_float4(acc[i][0], acc[i][1], acc[i][2], acc[i][3]);
        *(float4*)&out[(size_t)n * cHID + tc * 4] = v;
        float ps = v.x * as0 + v.y * as1v + v.z * as2v + v.w * as3;
        float pd = v.x * ad0 + v.y * ad1v + v.z * ad2v + v.w * ad3;
        ps += __shfl_xor(ps, 1); ps += __shfl_xor(ps, 2); ps += __shfl_xor(ps, 4);
        pd += __shfl_xor(pd, 1); pd += __shfl_xor(pd, 2); pd += __shfl_xor(pd, 4);
        if ((tc & 7) == 0) {
            es[n * cHEADS + head] = ps;
            ed[n * cHEADS + head] = pd;
        }
    }
}

// ---------------- GEMM 2 + fused scores: K=128, A fp32 contiguous ----------------
__global__ void gemm2_kernel(const float* A, const float* W,
                             const float* a_src, const float* a_dst,
                             float* out, float* es, float* ed) {
    __shared__ float As[32][36];
    __shared__ float Bs[32][132];
    int tid = threadIdx.x;
    int n0  = blockIdx.x * 32;
    int tc  = tid & 31;
    int tn  = tid >> 5;
    float acc[4][4] = {};

    for (int k0 = 0; k0 < cHID; k0 += 32) {
        for (int i = 0; i < 4; i++) {
            int p  = tid + i * 256;
            int nn = p >> 5, kk = p & 31;
            As[kk][nn] = A[(size_t)(n0 + nn) * cHID + k0 + kk];
        }
        for (int i = 0; i < 16; i++) {
            int p  = tid + i * 256;
            int c  = p >> 5, kk = p & 31;
            Bs[kk][c] = W[c * cHID + k0 + kk];
        }
        __syncthreads();
        #pragma unroll
        for (int kk = 0; kk < 32; kk++) {
            float a0 = As[kk][tn * 4 + 0], a1 = As[kk][tn * 4 + 1];
            float a2 = As[kk][tn * 4 + 2], a3 = As[kk][tn * 4 + 3];
            float b0 = Bs[kk][tc * 4 + 0], b1 = Bs[kk][tc * 4 + 1];
            float b2 = Bs[kk][tc * 4 + 2], b3 = Bs[kk][tc * 4 + 3];
            acc[0][0] += a0 * b0; acc[0][1] += a0 * b1; acc[0][2] += a0 * b2; acc[0][3] += a0 * b3;
            acc[1][0] += a1 * b0; acc[1][1] += a1 * b1; acc[1][2] += a1 * b2; acc[1][3] += a1 * b3;
            acc[2][0] += a2 * b0; acc[2][1] += a2 * b1; acc[2][2] += a2 * b2; acc[2][3] += a2 * b3;
            acc[3][0] += a3 * b0; acc[3][1] += a3 * b1; acc[3][2] += a3 * b2; acc[3][3] += a3 * b3;
        }
        __syncthreads();
    }
    float as0 = a_src[tc * 4 + 0], as1v = a_src[tc * 4 + 1], as2v = a_src[tc * 4 + 2], as3 = a_src[tc * 4 + 3];
    float ad0 = a_dst[tc * 4 + 0], ad1v = a_dst[tc * 4 + 1], ad2v = a_dst[tc * 4 + 2], ad3 = a_dst[tc * 4 + 3];
    int head = tc >> 3;
    #pragma unroll
    for (int i = 0; i < 4; i++) {
        int n = n0 + tn * 4 + i;
        float4 v = make_float4(acc[i][0], acc[i][1], acc[i][2], acc[i][3]);
        *(float4*)&out[(size_t)n * cHID + tc * 4] = v;
        float ps = v.x * as0 + v.y * as1v + v.z * as2v + v.w * as3;
        float pd = v.x * ad0 + v.y * ad1v + v.z * ad2v + v.w * ad3;
        ps += __shfl_xor(ps, 1); ps += __shfl_xor(ps, 2); ps += __shfl_xor(ps, 4);
        pd += __shfl_xor(pd, 1); pd += __shfl_xor(pd, 2); pd += __shfl_xor(pd, 4);
        if ((tc & 7) == 0) {
            es[n * cHEADS + head] = ps;
            ed[n * cHEADS + head] = pd;
        }
    }
}

// ---------------- softmax stats prepass: per (node,head) max + 1/denom ----------------
__global__ void stats_kernel(const float* es, const float* ed,
                             const int* offs, const int* csr,
                             float* m_arr, float* inv_arr) {
    int u = blockIdx.x * blockDim.x + threadIdx.x;   // u = n*4 + head
    if (u >= cN * cHEADS) return;
    int n = u >> 2, head = u & 3;
    int s0 = offs[n], s1 = offs[n + 1];
    float edn = ed[u];
    float m = -1e30f;
    for (int i = s0; i < s1; i++) {
        float sc = es[csr[i] * cHEADS + head] + edn;
        sc = (sc >= 0.f) ? sc : cLEAKY * sc;
        m = fmaxf(m, sc);
    }
    float den = 0.f;
    for (int i = s0; i < s1; i++) {
        float sc = es[csr[i] * cHEADS + head] + edn;
        sc = (sc >= 0.f) ? sc : cLEAKY * sc;
        den += __expf(sc - m);
    }
    m_arr[u]   = m;
    inv_arr[u] = 1.f / (den + 1e-16f);
}

// ---------------- layer-1 agg: single-pass weighted gather + bias + ELU ----------------
// 32 lanes per node (float4 per lane), 8 nodes per 256-thread block
__global__ void agg_kernel(const float* __restrict__ h, const float* __restrict__ es,
                           const float* __restrict__ ed, const float* __restrict__ m_arr,
                           const float* __restrict__ inv_arr,
                           const int* __restrict__ offs, const int* __restrict__ csr,
                           const float* __restrict__ bias, float* __restrict__ out) {
    int n = blockIdx.x * 8 + (threadIdx.x >> 5);
    int j = threadIdx.x & 31;          // feature group: floats 4j..4j+3
    int head = j >> 3;
    int u = n * cHEADS + head;
    int s0 = offs[n], s1 = offs[n + 1];
    float edn = ed[u], m = m_arr[u], inv = inv_arr[u];

    float4 acc = make_float4(0.f, 0.f, 0.f, 0.f);
    int i = s0;
    for (; i + 1 < s1; i += 2) {
        int sa = csr[i], sb = csr[i + 1];
        float4 ha = *(const float4*)(h + (size_t)sa * cHID + 4 * j);
        float4 hb = *(const float4*)(h + (size_t)sb * cHID + 4 * j);
        float ea = es[sa * cHEADS + head] + edn;
        float eb = es[sb * cHEADS + head] + edn;
        ea = (ea >= 0.f) ? ea : cLEAKY * ea;
        eb = (eb >= 0.f) ? eb : cLEAKY * eb;
        float wa = __expf(ea - m) * inv;
        float wb = __expf(eb - m) * inv;
        acc.x += wa * ha.x + wb * hb.x;
        acc.y += wa * ha.y + wb * hb.y;
        acc.z += wa * ha.z + wb * hb.z;
        acc.w += wa * ha.w + wb * hb.w;
    }
    if (i < s1) {
        int sa = csr[i];
        float4 ha = *(const float4*)(h + (size_t)sa * cHID + 4 * j);
        float ea = es[sa * cHEADS + head] + edn;
        ea = (ea >= 0.f) ? ea : cLEAKY * ea;
        float wa = __expf(ea - m) * inv;
        acc.x += wa * ha.x; acc.y += wa * ha.y; acc.z += wa * ha.z; acc.w += wa * ha.w;
    }
    float4 b4 = *(const float4*)(bias + 4 * j);
    float4 r;
    r.x = acc.x + b4.x; r.x = (r.x > 0.f) ? r.x : expm1f(r.x);
    r.y = acc.y + b4.y; r.y = (r.y > 0.f) ? r.y : expm1f(r.y);
    r.z = acc.z + b4.z; r.z = (r.z > 0.f) ? r.z : expm1f(r.z);
    r.w = acc.w + b4.w; r.w = (r.w > 0.f) ? r.w : expm1f(r.w);
    *(float4*)(out + (size_t)n * cHID + 4 * j) = r;
}

// ---------------- layer-2 agg + fused MLP head -> y[n] (one fp32 per node) ----------------
// same gather structure; then node vector round-trips 4KB LDS, each thread one (node,j) dot
__global__ void TemporalGAT_20005957665499_kernel(
        const float* __restrict__ h, const float* __restrict__ es,
        const float* __restrict__ ed, const float* __restrict__ m_arr,
        const float* __restrict__ inv_arr,
        const int* __restrict__ offs, const int* __restrict__ csr,
        const float* __restrict__ bias,
        const float* __restrict__ lw1, const float* __restrict__ lb1,
        const float* __restrict__ lw2, const float* __restrict__ lb2,
        float* __restrict__ out) {
    __shared__ float lw1s[32 * 129];   // stride 129: bank = (j+k)%32 -> conflict-free
    __shared__ float xs[8][128];       // per-node MLP input (reads are 32-lane broadcasts)
    __shared__ float lw2s[32];
    __shared__ float lb1s[32];
    int tid = threadIdx.x;
    for (int i = tid; i < 4096; i += 256)
        lw1s[(i >> 7) * 129 + (i & 127)] = lw1[i];
    if (tid < 32) { lw2s[tid] = lw2[tid]; lb1s[tid] = lb1[tid]; }

    int node = tid >> 5;
    int n = blockIdx.x * 8 + node;
    int j = tid & 31;
    int head = j >> 3;
    int u = n * cHEADS + head;
    int s0 = offs[n], s1 = offs[n + 1];
    float edn = ed[u], m = m_arr[u], inv = inv_arr[u];

    float4 acc = make_float4(0.f, 0.f, 0.f, 0.f);
    int i = s0;
    for (; i + 1 < s1; i += 2) {
        int sa = csr[i], sb = csr[i + 1];
        float4 ha = *(const float4*)(h + (size_t)sa * cHID + 4 * j);
        float4 hb = *(const float4*)(h + (size_t)sb * cHID + 4 * j);
        float ea = es[sa * cHEADS + head] + edn;
        float eb = es[sb * cHEADS + head] + edn;
        ea = (ea >= 0.f) ? ea : cLEAKY * ea;
        eb = (eb >= 0.f) ? eb : cLEAKY * eb;
        float wa = __expf(ea - m) * inv;
        float wb = __expf(eb - m) * inv;
        acc.x += wa * ha.x + wb * hb.x;
        acc.y += wa * ha.y + wb * hb.y;
        acc.z += wa * ha.z + wb * hb.z;
        acc.w += wa * ha.w + wb * hb.w;
    }
    if (i < s1) {
        int sa = csr[i];
        float4 ha = *(const float4*)(h + (size_t)sa * cHID + 4 * j);
        float ea = es[sa * cHEADS + head] + edn;
        ea = (ea >= 0.f) ? ea : cLEAKY * ea;
        float wa = __expf(ea - m) * inv;
        acc.x += wa * ha.x; acc.y += wa * ha.y; acc.z += wa * ha.z; acc.w += wa * ha.w;
    }
    float4 b4 = *(const float4*)(bias + 4 * j);
    float4 r;
    r.x = acc.x + b4.x; r.x = (r.x > 0.f) ? r.x : expm1f(r.x);
    r.y = acc.y + b4.y; r.y = (r.y > 0.f) ? r.y : expm1f(r.y);
    r.z = acc.z + b4.z; r.z = (r.z > 0.f) ? r.z : expm1f(r.z);
    r.w = acc.w + b4.w; r.w = (r.w > 0.f) ? r.w : expm1f(r.w);
    xs[node][4 * j + 0] = r.x;
    xs[node][4 * j + 1] = r.y;
    xs[node][4 * j + 2] = r.z;
    xs[node][4 * j + 3] = r.w;
    __syncthreads();

    // MLP: thread (node, j) computes relu(dot(xs[node], lw1[j]) + lb1[j]) * lw2[j]
    const float* xrow = xs[node];
    const float* wrow = &lw1s[j * 129];
    float s = 0.f;
    #pragma unroll 8
    for (int k = 0; k < cHID; k++) s += xrow[k] * wrow[k];
    s += lb1s[j];
    s = fmaxf(s, 0.f);
    float v = s * lw2s[j];
    v += __shfl_xor(v, 16);
    v += __shfl_xor(v, 8);
    v += __shfl_xor(v, 4);
    v += __shfl_xor(v, 2);
    v += __shfl_xor(v, 1);
    if (j == 0) out[n] = v + lb2[0];
}

// ---------------- launch ----------------
extern "C" void kernel_launch(void* const* d_in, const int* in_sizes, int n_in,
                              void* d_out, int out_size, void* d_ws, size_t ws_size,
                              hipStream_t stream) {
    const float* x   = (const float*)d_in[0];   // [N,T,64] fp32
    const int*   ei  = (const int*)d_in[1];     // [2,E] int32
    const float* W1  = (const float*)d_in[2];   // [128,64]
    const float* as1 = (const float*)d_in[3];   // [4,32]
    const float* ad1 = (const float*)d_in[4];
    const float* b1  = (const float*)d_in[5];   // [128]
    const float* W2  = (const float*)d_in[6];   // [128,128]
    const float* as2 = (const float*)d_in[7];
    const float* ad2 = (const float*)d_in[8];
    const float* b2  = (const float*)d_in[9];
    const float* lw1 = (const float*)d_in[10];  // [32,128]
    const float* lb1 = (const float*)d_in[11];  // [32]
    const float* lw2 = (const float*)d_in[12];  // [1,32]
    const float* lb2 = (const float*)d_in[13];  // [1]
    float* out = (float*)d_out;                 // [T,N,1] fp32
    (void)in_sizes; (void)n_in; (void)out_size; (void)ws_size;

    // workspace carve, 256B-aligned (~24 MB of 256 MB)
    char* ws = (char*)d_ws;
    size_t o = 0;
    float* h_buf   = (float*)(ws + o); o += (((size_t)cN * cHID * 4)   + 255) & ~(size_t)255;
    float* x_buf   = (float*)(ws + o); o += (((size_t)cN * cHID * 4)   + 255) & ~(size_t)255;
    float* es_buf  = (float*)(ws + o); o += (((size_t)cN * cHEADS * 4) + 255) & ~(size_t)255;
    float* ed_buf  = (float*)(ws + o); o += (((size_t)cN * cHEADS * 4) + 255) & ~(size_t)255;
    float* m_buf   = (float*)(ws + o); o += (((size_t)cN * cHEADS * 4) + 255) & ~(size_t)255;
    float* inv_buf = (float*)(ws + o); o += (((size_t)cN * cHEADS * 4) + 255) & ~(size_t)255;
    int*   deg     = (int*)(ws + o);   o += (((size_t)cN * 4)          + 255) & ~(size_t)255;
    int*   offs    = (int*)(ws + o);   o += (((size_t)(cN + 1) * 4)    + 255) & ~(size_t)255;
    int*   cursor  = (int*)(ws + o);   o += (((size_t)cN * 4)          + 255) & ~(size_t)255;
    int*   csr     = (int*)(ws + o);   o += (((size_t)cET * 4)         + 255) & ~(size_t)255;

    // ---- CSR build (edge_index launch-invariant; rebuilt every call) ----
    deg_init_kernel<<<(cN + 255) / 256, 256, 0, stream>>>(deg);
    deg_count_kernel<<<(cE + 255) / 256, 256, 0, stream>>>(ei, deg);
    scan_kernel<<<1, 256, 0, stream>>>(deg, offs);
    cursor_copy_kernel<<<(cN + 255) / 256, 256, 0, stream>>>(offs, cursor);
    scatter_kernel<<<(cET + 255) / 256, 256, 0, stream>>>(ei, cursor, csr);

    const int NH_G = (cN * cHEADS + 255) / 256;
    for (int t = 0; t < cT; t++) {
        // layer 1 (scores fused into GEMM epilogue)
        gemm1_kernel<<<cN / 32, 256, 0, stream>>>(x + t * cFIN, cT * cFIN, W1, as1, ad1,
                                                  h_buf, es_buf, ed_buf);
        stats_kernel<<<NH_G, 256, 0, stream>>>(es_buf, ed_buf, offs, csr, m_buf, inv_buf);
        agg_kernel<<<cN / 8, 256, 0, stream>>>(h_buf, es_buf, ed_buf, m_buf, inv_buf, offs, csr, b1, x_buf);
        // layer 2 (scores fused; agg fused with MLP head -> out)
        gemm2_kernel<<<cN / 32, 256, 0, stream>>>(x_buf, W2, as2, ad2, h_buf, es_buf, ed_buf);
        stats_kernel<<<NH_G, 256, 0, stream>>>(es_buf, ed_buf, offs, csr, m_buf, inv_buf);
        TemporalGAT_20005957665499_kernel<<<cN / 8, 256, 0, stream>>>(
            h_buf, es_buf, ed_buf, m_buf, inv_buf, offs, csr, b2,
            lw1, lb1, lw2, lb2, out + (size_t)t * cN);
    }
}

// Round 9
// 1198.396 us; speedup vs baseline: 1.6634x; 1.0059x over previous
//
#include <hip/hip_runtime.h>

// ---------------- problem constants ----------------
constexpr int cN     = 20000;
constexpr int cT     = 8;
constexpr int cFIN   = 64;
constexpr int cHEADS = 4;
constexpr int cF     = 32;
constexpr int cHID   = 128;        // cHEADS * cF
constexpr int cE     = 320000;
constexpr int cET    = cE + cN;    // edges + self loops
constexpr float cLEAKY = 0.2f;

typedef __attribute__((ext_vector_type(8))) short bf16x8;   // MFMA A/B frag (4 VGPRs)
typedef __attribute__((ext_vector_type(4))) float f32x4;    // MFMA C/D frag

// fp32 -> bf16 raw bits, round-to-nearest-even
static __device__ __forceinline__ unsigned short f2bfu(float f) {
    unsigned int u;
    __builtin_memcpy(&u, &f, 4);
    u += 0x7FFFu + ((u >> 16) & 1u);
    return (unsigned short)(u >> 16);
}

// ---------------- dtype conversion ----------------
// x [N,T,64] fp32 -> xb [T,N,64] bf16 (per-t packed rows for GEMM1)
__global__ void cvt_x_kernel(const float* x, unsigned short* xb) {
    int id = blockIdx.x * 256 + threadIdx.x;        // over n*64+k
    int t  = blockIdx.y;
    int k  = id & 63;
    int n  = id >> 6;
    xb[(size_t)t * cN * cFIN + id] = f2bfu(x[(size_t)n * (cT * cFIN) + t * cFIN + k]);
}

__global__ void cvt_kernel(const float* s, unsigned short* d, int n) {
    int i = blockIdx.x * 256 + threadIdx.x;
    if (i < n) d[i] = f2bfu(s[i]);
}

// ---------------- CSR build ----------------
__global__ void deg_init_kernel(int* deg) {
    int n = blockIdx.x * blockDim.x + threadIdx.x;
    if (n < cN) deg[n] = 1;   // self loop
}

__global__ void deg_count_kernel(const int* ei, int* deg) {
    int e = blockIdx.x * blockDim.x + threadIdx.x;
    if (e < cE) atomicAdd(&deg[ei[cE + e]], 1);   // dst = edge_index[1][e]
}

__global__ void scan_kernel(const int* deg, int* offs) {
    __shared__ int lds[256];
    const int CH = 80;                 // 256*80 = 20480 >= cN
    int tid  = threadIdx.x;
    int base = tid * CH;
    int tot = 0;
    for (int j = 0; j < CH; j++) {
        int idx = base + j;
        if (idx < cN) tot += deg[idx];
    }
    lds[tid] = tot;
    __syncthreads();
    for (int off = 1; off < 256; off <<= 1) {
        int v = (tid >= off) ? lds[tid - off] : 0;
        __syncthreads();
        lds[tid] += v;
        __syncthreads();
    }
    int run = lds[tid] - tot;
    for (int j = 0; j < CH; j++) {
        int idx = base + j;
        if (idx < cN) { offs[idx] = run; run += deg[idx]; }
    }
    if (tid == 255) offs[cN] = lds[255];
}

__global__ void cursor_copy_kernel(const int* offs, int* cur) {
    int n = blockIdx.x * blockDim.x + threadIdx.x;
    if (n < cN) cur[n] = offs[n];
}

__global__ void scatter_kernel(const int* ei, int* cur, int* csr) {
    int e = blockIdx.x * blockDim.x + threadIdx.x;
    if (e >= cET) return;
    int s, d;
    if (e < cE) { s = ei[e]; d = ei[cE + e]; }
    else        { s = e - cE; d = s; }
    int pos = atomicAdd(&cur[d], 1);
    csr[pos] = s;
}

// ---------------- MFMA GEMM + fused scores ----------------
// C[n, c] = sum_k A[n,k]*W[c,k], A [N,K] bf16 packed, W [128,K] bf16.
// 256 thr = 4 waves; wave w computes rows m0..m0+15 x all 128 cols via
// 8 col-tiles of 16x16x32 MFMA. A/B frags: 8 contiguous k per lane
// (A: m=lane&15, k=quad*8+j; B: c=lane&15, k=quad*8+j). Frags read direct
// from global (W is L1/L2-hot, A rows touched once). C/D: col=lane&15,
// row=quad*4+reg. Epilogue: C tile -> LDS -> per-(row,head) score dots.
template<int K>
__global__ __launch_bounds__(256) void gemm_mfma_kernel(
        const unsigned short* __restrict__ A, const unsigned short* __restrict__ W,
        const float* __restrict__ a_src, const float* __restrict__ a_dst,
        float* __restrict__ h, float* __restrict__ es, float* __restrict__ ed) {
    __shared__ float hl[64][132];      // 33 KB; write pattern 2-way conflict (free)
    int tid  = threadIdx.x;
    int wave = tid >> 6;
    int lane = tid & 63;
    int q    = lane >> 4;
    int mi   = lane & 15;
    int m0   = blockIdx.x * 64 + wave * 16;

    int arow = m0 + mi;
    if (arow > cN - 1) arow = cN - 1;   // clamp tail loads
    bf16x8 afrag[K / 32];
    #pragma unroll
    for (int s = 0; s < K / 32; s++)
        afrag[s] = *(const bf16x8*)(A + (size_t)arow * K + s * 32 + q * 8);

    f32x4 acc[8];
    #pragma unroll
    for (int ct = 0; ct < 8; ct++) acc[ct] = (f32x4){0.f, 0.f, 0.f, 0.f};

    #pragma unroll
    for (int ct = 0; ct < 8; ct++) {
        int c = ct * 16 + mi;
        #pragma unroll
        for (int s = 0; s < K / 32; s++) {
            bf16x8 bfrag = *(const bf16x8*)(W + (size_t)c * K + s * 32 + q * 8);
            acc[ct] = __builtin_amdgcn_mfma_f32_16x16x32_bf16(afrag[s], bfrag, acc[ct], 0, 0, 0);
        }
    }

    // epilogue: store h (fp32) + stage tile in LDS for scores
    #pragma unroll
    for (int ct = 0; ct < 8; ct++) {
        #pragma unroll
        for (int r = 0; r < 4; r++) {
            int rr = q * 4 + r;
            int n  = m0 + rr;
            int c  = ct * 16 + mi;
            hl[wave * 16 + rr][c] = acc[ct][r];
            if (n < cN) h[(size_t)n * cHID + c] = acc[ct][r];
        }
    }
    __syncthreads();

    // scores: wave hd handles head hd for all 64 rows of the block
    int r2 = tid & 63;
    int hd = tid >> 6;
    int n2 = blockIdx.x * 64 + r2;
    if (n2 < cN) {
        const float* hr = &hl[r2][hd * cF];
        const float* sa = a_src + hd * cF;
        const float* da = a_dst + hd * cF;
        float s1 = 0.f, s2 = 0.f;
        #pragma unroll 8
        for (int f = 0; f < cF; f++) {
            float hv = hr[f];
            s1 += hv * sa[f];
            s2 += hv * da[f];
        }
        es[n2 * cHEADS + hd] = s1;
        ed[n2 * cHEADS + hd] = s2;
    }
}

// ---------------- softmax stats prepass: per (node,head) max + 1/denom ----------------
__global__ void stats_kernel(const float* es, const float* ed,
                             const int* offs, const int* csr,
                             float* m_arr, float* inv_arr) {
    int u = blockIdx.x * blockDim.x + threadIdx.x;   // u = n*4 + head
    if (u >= cN * cHEADS) return;
    int n = u >> 2, head = u & 3;
    int s0 = offs[n], s1 = offs[n + 1];
    float edn = ed[u];
    float m = -1e30f;
    for (int i = s0; i < s1; i++) {
        float sc = es[csr[i] * cHEADS + head] + edn;
        sc = (sc >= 0.f) ? sc : cLEAKY * sc;
        m = fmaxf(m, sc);
    }
    float den = 0.f;
    for (int i = s0; i < s1; i++) {
        float sc = es[csr[i] * cHEADS + head] + edn;
        sc = (sc >= 0.f) ? sc : cLEAKY * sc;
        den += __expf(sc - m);
    }
    m_arr[u]   = m;
    inv_arr[u] = 1.f / (den + 1e-16f);
}

// ---------------- layer-1 agg: gather + bias + ELU -> bf16 rows for GEMM2 ----------------
// 32 lanes per node (float4 per lane), 8 nodes per 256-thread block
__global__ void agg_kernel(const float* __restrict__ h, const float* __restrict__ es,
                           const float* __restrict__ ed, const float* __restrict__ m_arr,
                           const float* __restrict__ inv_arr,
                           const int* __restrict__ offs, const int* __restrict__ csr,
                           const float* __restrict__ bias, unsigned short* __restrict__ outb) {
    int n = blockIdx.x * 8 + (threadIdx.x >> 5);
    int j = threadIdx.x & 31;          // feature group: floats 4j..4j+3
    int head = j >> 3;
    int u = n * cHEADS + head;
    int s0 = offs[n], s1 = offs[n + 1];
    float edn = ed[u], m = m_arr[u], inv = inv_arr[u];

    float4 acc = make_float4(0.f, 0.f, 0.f, 0.f);
    int i = s0;
    for (; i + 1 < s1; i += 2) {
        int sa = csr[i], sb = csr[i + 1];
        float4 ha = *(const float4*)(h + (size_t)sa * cHID + 4 * j);
        float4 hb = *(const float4*)(h + (size_t)sb * cHID + 4 * j);
        float ea = es[sa * cHEADS + head] + edn;
        float eb = es[sb * cHEADS + head] + edn;
        ea = (ea >= 0.f) ? ea : cLEAKY * ea;
        eb = (eb >= 0.f) ? eb : cLEAKY * eb;
        float wa = __expf(ea - m) * inv;
        float wb = __expf(eb - m) * inv;
        acc.x += wa * ha.x + wb * hb.x;
        acc.y += wa * ha.y + wb * hb.y;
        acc.z += wa * ha.z + wb * hb.z;
        acc.w += wa * ha.w + wb * hb.w;
    }
    if (i < s1) {
        int sa = csr[i];
        float4 ha = *(const float4*)(h + (size_t)sa * cHID + 4 * j);
        float ea = es[sa * cHEADS + head] + edn;
        ea = (ea >= 0.f) ? ea : cLEAKY * ea;
        float wa = __expf(ea - m) * inv;
        acc.x += wa * ha.x; acc.y += wa * ha.y; acc.z += wa * ha.z; acc.w += wa * ha.w;
    }
    float4 b4 = *(const float4*)(bias + 4 * j);
    float rx = acc.x + b4.x; rx = (rx > 0.f) ? rx : expm1f(rx);
    float ry = acc.y + b4.y; ry = (ry > 0.f) ? ry : expm1f(ry);
    float rz = acc.z + b4.z; rz = (rz > 0.f) ? rz : expm1f(rz);
    float rw = acc.w + b4.w; rw = (rw > 0.f) ? rw : expm1f(rw);
    ushort4 o;
    o.x = f2bfu(rx); o.y = f2bfu(ry); o.z = f2bfu(rz); o.w = f2bfu(rw);
    *(ushort4*)(outb + (size_t)n * cHID + 4 * j) = o;
}

// ---------------- layer-2 agg + fused MLP head -> y[n] ----------------
__global__ void TemporalGAT_20005957665499_kernel(
        const float* __restrict__ h, const float* __restrict__ es,
        const float* __restrict__ ed, const float* __restrict__ m_arr,
        const float* __restrict__ inv_arr,
        const int* __restrict__ offs, const int* __restrict__ csr,
        const float* __restrict__ bias,
        const float* __restrict__ lw1, const float* __restrict__ lb1,
        const float* __restrict__ lw2, const float* __restrict__ lb2,
        float* __restrict__ out) {
    __shared__ float lw1s[32 * 129];   // stride 129: conflict-free
    __shared__ float xs[8][128];
    __shared__ float lw2s[32];
    __shared__ float lb1s[32];
    int tid = threadIdx.x;
    for (int i = tid; i < 4096; i += 256)
        lw1s[(i >> 7) * 129 + (i & 127)] = lw1[i];
    if (tid < 32) { lw2s[tid] = lw2[tid]; lb1s[tid] = lb1[tid]; }

    int node = tid >> 5;
    int n = blockIdx.x * 8 + node;
    int j = tid & 31;
    int head = j >> 3;
    int u = n * cHEADS + head;
    int s0 = offs[n], s1 = offs[n + 1];
    float edn = ed[u], m = m_arr[u], inv = inv_arr[u];

    float4 acc = make_float4(0.f, 0.f, 0.f, 0.f);
    int i = s0;
    for (; i + 1 < s1; i += 2) {
        int sa = csr[i], sb = csr[i + 1];
        float4 ha = *(const float4*)(h + (size_t)sa * cHID + 4 * j);
        float4 hb = *(const float4*)(h + (size_t)sb * cHID + 4 * j);
        float ea = es[sa * cHEADS + head] + edn;
        float eb = es[sb * cHEADS + head] + edn;
        ea = (ea >= 0.f) ? ea : cLEAKY * ea;
        eb = (eb >= 0.f) ? eb : cLEAKY * eb;
        float wa = __expf(ea - m) * inv;
        float wb = __expf(eb - m) * inv;
        acc.x += wa * ha.x + wb * hb.x;
        acc.y += wa * ha.y + wb * hb.y;
        acc.z += wa * ha.z + wb * hb.z;
        acc.w += wa * ha.w + wb * hb.w;
    }
    if (i < s1) {
        int sa = csr[i];
        float4 ha = *(const float4*)(h + (size_t)sa * cHID + 4 * j);
        float ea = es[sa * cHEADS + head] + edn;
        ea = (ea >= 0.f) ? ea : cLEAKY * ea;
        float wa = __expf(ea - m) * inv;
        acc.x += wa * ha.x; acc.y += wa * ha.y; acc.z += wa * ha.z; acc.w += wa * ha.w;
    }
    float4 b4 = *(const float4*)(bias + 4 * j);
    float4 r;
    r.x = acc.x + b4.x; r.x = (r.x > 0.f) ? r.x : expm1f(r.x);
    r.y = acc.y + b4.y; r.y = (r.y > 0.f) ? r.y : expm1f(r.y);
    r.z = acc.z + b4.z; r.z = (r.z > 0.f) ? r.z : expm1f(r.z);
    r.w = acc.w + b4.w; r.w = (r.w > 0.f) ? r.w : expm1f(r.w);
    xs[node][4 * j + 0] = r.x;
    xs[node][4 * j + 1] = r.y;
    xs[node][4 * j + 2] = r.z;
    xs[node][4 * j + 3] = r.w;
    __syncthreads();

    const float* xrow = xs[node];
    const float* wrow = &lw1s[j * 129];
    float s = 0.f;
    #pragma unroll 8
    for (int k = 0; k < cHID; k++) s += xrow[k] * wrow[k];
    s += lb1s[j];
    s = fmaxf(s, 0.f);
    float v = s * lw2s[j];
    v += __shfl_xor(v, 16);
    v += __shfl_xor(v, 8);
    v += __shfl_xor(v, 4);
    v += __shfl_xor(v, 2);
    v += __shfl_xor(v, 1);
    if (j == 0) out[n] = v + lb2[0];
}

// ---------------- launch ----------------
extern "C" void kernel_launch(void* const* d_in, const int* in_sizes, int n_in,
                              void* d_out, int out_size, void* d_ws, size_t ws_size,
                              hipStream_t stream) {
    const float* x   = (const float*)d_in[0];   // [N,T,64] fp32
    const int*   ei  = (const int*)d_in[1];     // [2,E] int32
    const float* W1  = (const float*)d_in[2];   // [128,64]
    const float* as1 = (const float*)d_in[3];   // [4,32]
    const float* ad1 = (const float*)d_in[4];
    const float* b1  = (const float*)d_in[5];   // [128]
    const float* W2  = (const float*)d_in[6];   // [128,128]
    const float* as2 = (const float*)d_in[7];
    const float* ad2 = (const float*)d_in[8];
    const float* b2  = (const float*)d_in[9];
    const float* lw1 = (const float*)d_in[10];  // [32,128]
    const float* lb1 = (const float*)d_in[11];  // [32]
    const float* lw2 = (const float*)d_in[12];  // [1,32]
    const float* lb2 = (const float*)d_in[13];  // [1]
    float* out = (float*)d_out;                 // [T,N,1] fp32
    (void)in_sizes; (void)n_in; (void)out_size; (void)ws_size;

    // workspace carve, 256B-aligned (~50 MB of 256 MB)
    char* ws = (char*)d_ws;
    size_t o = 0;
    float* h_buf   = (float*)(ws + o); o += (((size_t)cN * cHID * 4)   + 255) & ~(size_t)255;
    float* es_buf  = (float*)(ws + o); o += (((size_t)cN * cHEADS * 4) + 255) & ~(size_t)255;
    float* ed_buf  = (float*)(ws + o); o += (((size_t)cN * cHEADS * 4) + 255) & ~(size_t)255;
    float* m_buf   = (float*)(ws + o); o += (((size_t)cN * cHEADS * 4) + 255) & ~(size_t)255;
    float* inv_buf = (float*)(ws + o); o += (((size_t)cN * cHEADS * 4) + 255) & ~(size_t)255;
    int*   deg     = (int*)(ws + o);   o += (((size_t)cN * 4)          + 255) & ~(size_t)255;
    int*   offs    = (int*)(ws + o);   o += (((size_t)(cN + 1) * 4)    + 255) & ~(size_t)255;
    int*   cursor  = (int*)(ws + o);   o += (((size_t)cN * 4)          + 255) & ~(size_t)255;
    int*   csr     = (int*)(ws + o);   o += (((size_t)cET * 4)         + 255) & ~(size_t)255;
    unsigned short* xb  = (unsigned short*)(ws + o); o += (((size_t)cT * cN * cFIN * 2) + 255) & ~(size_t)255;
    unsigned short* xb2 = (unsigned short*)(ws + o); o += (((size_t)cN * cHID * 2)      + 255) & ~(size_t)255;
    unsigned short* W1b = (unsigned short*)(ws + o); o += ((size_t)(cHID * cFIN * 2)    + 255) & ~(size_t)255;
    unsigned short* W2b = (unsigned short*)(ws + o); o += ((size_t)(cHID * cHID * 2)    + 255) & ~(size_t)255;

    // ---- one-time conversions (per call) ----
    cvt_x_kernel<<<dim3(cN * cFIN / 256, cT), 256, 0, stream>>>(x, xb);
    cvt_kernel<<<(cHID * cFIN + 255) / 256, 256, 0, stream>>>(W1, W1b, cHID * cFIN);
    cvt_kernel<<<(cHID * cHID + 255) / 256, 256, 0, stream>>>(W2, W2b, cHID * cHID);

    // ---- CSR build (edge_index launch-invariant; rebuilt every call) ----
    deg_init_kernel<<<(cN + 255) / 256, 256, 0, stream>>>(deg);
    deg_count_kernel<<<(cE + 255) / 256, 256, 0, stream>>>(ei, deg);
    scan_kernel<<<1, 256, 0, stream>>>(deg, offs);
    cursor_copy_kernel<<<(cN + 255) / 256, 256, 0, stream>>>(offs, cursor);
    scatter_kernel<<<(cET + 255) / 256, 256, 0, stream>>>(ei, cursor, csr);

    const int NH_G = (cN * cHEADS + 255) / 256;
    const int GEMM_G = (cN + 63) / 64;
    for (int t = 0; t < cT; t++) {
        // layer 1 (MFMA GEMM, scores fused)
        gemm_mfma_kernel<cFIN><<<GEMM_G, 256, 0, stream>>>(xb + (size_t)t * cN * cFIN, W1b,
                                                           as1, ad1, h_buf, es_buf, ed_buf);
        stats_kernel<<<NH_G, 256, 0, stream>>>(es_buf, ed_buf, offs, csr, m_buf, inv_buf);
        agg_kernel<<<cN / 8, 256, 0, stream>>>(h_buf, es_buf, ed_buf, m_buf, inv_buf, offs, csr, b1, xb2);
        // layer 2 (MFMA GEMM, scores fused; agg fused with MLP head -> out)
        gemm_mfma_kernel<cHID><<<GEMM_G, 256, 0, stream>>>(xb2, W2b, as2, ad2, h_buf, es_buf, ed_buf);
        stats_kernel<<<NH_G, 256, 0, stream>>>(es_buf, ed_buf, offs, csr, m_buf, inv_buf);
        TemporalGAT_20005957665499_kernel<<<cN / 8, 256, 0, stream>>>(
            h_buf, es_buf, ed_buf, m_buf, inv_buf, offs, csr, b2,
            lw1, lb1, lw2, lb2, out + (size_t)t * cN);
    }
}

// Round 10
// 586.976 us; speedup vs baseline: 3.3961x; 2.0416x over previous
//
#include <hip/hip_runtime.h>

// ---------------- problem constants ----------------
constexpr int cN     = 20000;
constexpr int cT     = 8;
constexpr int cFIN   = 64;
constexpr int cHEADS = 4;
constexpr int cF     = 32;
constexpr int cHID   = 128;        // cHEADS * cF
constexpr int cE     = 320000;
constexpr int cET    = cE + cN;    // edges + self loops
constexpr int cR     = cN * cT;    // 160000 batched rows, r = n*8 + t
constexpr float cLEAKY = 0.2f;

typedef __attribute__((ext_vector_type(8))) short bf16x8;   // MFMA A/B frag
typedef __attribute__((ext_vector_type(4))) float f32x4;    // MFMA C/D frag

static __device__ __forceinline__ unsigned short f2bfu(float f) {
    unsigned int u;
    __builtin_memcpy(&u, &f, 4);
    u += 0x7FFFu + ((u >> 16) & 1u);
    return (unsigned short)(u >> 16);
}
static __device__ __forceinline__ float bfu2f(unsigned short b) {
    unsigned int u = ((unsigned int)b) << 16;
    float f;
    __builtin_memcpy(&f, &u, 4);
    return f;
}
static __device__ __forceinline__ float4 bf4tof4(ushort4 v) {
    return make_float4(bfu2f(v.x), bfu2f(v.y), bfu2f(v.z), bfu2f(v.w));
}

// ---------------- dtype conversion (flat) ----------------
__global__ void cvt_kernel(const float* s, unsigned short* d, int n) {
    int i = blockIdx.x * 256 + threadIdx.x;
    if (i < n) d[i] = f2bfu(s[i]);
}

// ---------------- CSR build ----------------
__global__ void deg_init_kernel(int* deg) {
    int n = blockIdx.x * blockDim.x + threadIdx.x;
    if (n < cN) deg[n] = 1;   // self loop
}
__global__ void deg_count_kernel(const int* ei, int* deg) {
    int e = blockIdx.x * blockDim.x + threadIdx.x;
    if (e < cE) atomicAdd(&deg[ei[cE + e]], 1);
}
__global__ void scan_kernel(const int* deg, int* offs) {
    __shared__ int lds[256];
    const int CH = 80;
    int tid  = threadIdx.x;
    int base = tid * CH;
    int tot = 0;
    for (int j = 0; j < CH; j++) {
        int idx = base + j;
        if (idx < cN) tot += deg[idx];
    }
    lds[tid] = tot;
    __syncthreads();
    for (int off = 1; off < 256; off <<= 1) {
        int v = (tid >= off) ? lds[tid - off] : 0;
        __syncthreads();
        lds[tid] += v;
        __syncthreads();
    }
    int run = lds[tid] - tot;
    for (int j = 0; j < CH; j++) {
        int idx = base + j;
        if (idx < cN) { offs[idx] = run; run += deg[idx]; }
    }
    if (tid == 255) offs[cN] = lds[255];
}
__global__ void cursor_copy_kernel(const int* offs, int* cur) {
    int n = blockIdx.x * blockDim.x + threadIdx.x;
    if (n < cN) cur[n] = offs[n];
}
__global__ void scatter_kernel(const int* ei, int* cur, int* csr) {
    int e = blockIdx.x * blockDim.x + threadIdx.x;
    if (e >= cET) return;
    int s, d;
    if (e < cE) { s = ei[e]; d = ei[cE + e]; }
    else        { s = e - cE; d = s; }
    int pos = atomicAdd(&cur[d], 1);
    csr[pos] = s;
}

// ---------------- batched MFMA GEMM + fused scores ----------------
// C[r,c] = sum_k A[r,k]*W[c,k] over all R=160000 rows (r=n*8+t).
// 256 thr = 4 waves; wave computes 16 rows x 128 cols (8 tiles 16x16x32).
// Output: hb bf16 [R,128] (coalesced via LDS) + es/ed fp32 [R*4].
template<int K>
__global__ __launch_bounds__(256) void gemm_mfma_kernel(
        const unsigned short* __restrict__ A, const unsigned short* __restrict__ W,
        const float* __restrict__ a_src, const float* __restrict__ a_dst,
        unsigned short* __restrict__ hb, float* __restrict__ es, float* __restrict__ ed) {
    __shared__ float hl[64][132];      // 33.8 KB
    int tid  = threadIdx.x;
    int wave = tid >> 6;
    int lane = tid & 63;
    int q    = lane >> 4;
    int mi   = lane & 15;
    int m0   = blockIdx.x * 64 + wave * 16;   // R % 64 == 0: no tail

    bf16x8 afrag[K / 32];
    #pragma unroll
    for (int s = 0; s < K / 32; s++)
        afrag[s] = *(const bf16x8*)(A + (size_t)(m0 + mi) * K + s * 32 + q * 8);

    f32x4 acc[8];
    #pragma unroll
    for (int ct = 0; ct < 8; ct++) acc[ct] = (f32x4){0.f, 0.f, 0.f, 0.f};
    #pragma unroll
    for (int ct = 0; ct < 8; ct++) {
        int c = ct * 16 + mi;
        #pragma unroll
        for (int s = 0; s < K / 32; s++) {
            bf16x8 bfrag = *(const bf16x8*)(W + (size_t)c * K + s * 32 + q * 8);
            acc[ct] = __builtin_amdgcn_mfma_f32_16x16x32_bf16(afrag[s], bfrag, acc[ct], 0, 0, 0);
        }
    }

    // stage fp32 tile in LDS
    #pragma unroll
    for (int ct = 0; ct < 8; ct++)
        #pragma unroll
        for (int r = 0; r < 4; r++)
            hl[wave * 16 + q * 4 + r][ct * 16 + mi] = acc[ct][r];
    __syncthreads();

    // scores: wave hd handles head hd for all 64 rows
    {
        int r2 = tid & 63;
        int hd = tid >> 6;
        int rg = blockIdx.x * 64 + r2;
        const float* hr = &hl[r2][hd * cF];
        const float* sa = a_src + hd * cF;
        const float* da = a_dst + hd * cF;
        float s1 = 0.f, s2 = 0.f;
        #pragma unroll 8
        for (int f = 0; f < cF; f++) {
            float hv = hr[f];
            s1 += hv * sa[f];
            s2 += hv * da[f];
        }
        es[rg * cHEADS + hd] = s1;
        ed[rg * cHEADS + hd] = s2;
    }

    // coalesced bf16 writeout of the 64x128 tile
    size_t base = (size_t)blockIdx.x * 64 * cHID;
    #pragma unroll
    for (int it = 0; it < 8; it++) {
        int g   = tid + it * 256;        // float4 group id, 2048 total
        int row = g >> 5;
        int c4  = (g & 31) * 4;
        float4 v = *(const float4*)&hl[row][c4];
        ushort4 o;
        o.x = f2bfu(v.x); o.y = f2bfu(v.y); o.z = f2bfu(v.z); o.w = f2bfu(v.w);
        *(ushort4*)(hb + base + (size_t)row * cHID + c4) = o;
    }
}

// ---------------- batched softmax denom (no max pass; |sc| ~ 5) ----------------
__global__ void stats_kernel(const float* __restrict__ es, const float* __restrict__ ed,
                             const int* __restrict__ offs, const int* __restrict__ csr,
                             float* __restrict__ inv_arr) {
    int u = blockIdx.x * blockDim.x + threadIdx.x;   // u = r*4 + head, r = n*8+t
    if (u >= cR * cHEADS) return;
    int r = u >> 2, head = u & 3;
    int n = r >> 3, t = r & 7;
    int s0 = offs[n], s1 = offs[n + 1];
    float edn = ed[u];
    int th = t * cHEADS + head;
    float den = 0.f;
    for (int i = s0; i < s1; i++) {
        float sc = es[csr[i] * (cT * cHEADS) + th] + edn;
        sc = (sc >= 0.f) ? sc : cLEAKY * sc;
        den += __expf(sc);
    }
    inv_arr[u] = 1.f / (den + 1e-16f);
}

// ---------------- batched layer-1 agg: gather bf16 + bias + ELU -> bf16 ----------------
// 32 lanes per row (ushort4 -> float4 per lane), 8 rows per 256-thread block
__global__ void agg_kernel(const unsigned short* __restrict__ hb, const float* __restrict__ es,
                           const float* __restrict__ ed, const float* __restrict__ inv_arr,
                           const int* __restrict__ offs, const int* __restrict__ csr,
                           const float* __restrict__ bias, unsigned short* __restrict__ outb) {
    int r = blockIdx.x * 8 + (threadIdx.x >> 5);
    int j = threadIdx.x & 31;
    int head = j >> 3;
    int n = r >> 3, t = r & 7;
    int u = r * cHEADS + head;
    int s0 = offs[n], s1 = offs[n + 1];
    float edn = ed[u], inv = inv_arr[u];
    int th = t * cHEADS + head;
    int tbase = t * cHID;   // row offset of timestep t within node stride

    float4 acc = make_float4(0.f, 0.f, 0.f, 0.f);
    int i = s0;
    for (; i + 1 < s1; i += 2) {
        int sa = csr[i], sb = csr[i + 1];
        float4 ha = bf4tof4(*(const ushort4*)(hb + (size_t)sa * (cT * cHID) + tbase + 4 * j));
        float4 hx = bf4tof4(*(const ushort4*)(hb + (size_t)sb * (cT * cHID) + tbase + 4 * j));
        float ea = es[sa * (cT * cHEADS) + th] + edn;
        float eb = es[sb * (cT * cHEADS) + th] + edn;
        ea = (ea >= 0.f) ? ea : cLEAKY * ea;
        eb = (eb >= 0.f) ? eb : cLEAKY * eb;
        float wa = __expf(ea) * inv;
        float wb = __expf(eb) * inv;
        acc.x += wa * ha.x + wb * hx.x;
        acc.y += wa * ha.y + wb * hx.y;
        acc.z += wa * ha.z + wb * hx.z;
        acc.w += wa * ha.w + wb * hx.w;
    }
    if (i < s1) {
        int sa = csr[i];
        float4 ha = bf4tof4(*(const ushort4*)(hb + (size_t)sa * (cT * cHID) + tbase + 4 * j));
        float ea = es[sa * (cT * cHEADS) + th] + edn;
        ea = (ea >= 0.f) ? ea : cLEAKY * ea;
        float wa = __expf(ea) * inv;
        acc.x += wa * ha.x; acc.y += wa * ha.y; acc.z += wa * ha.z; acc.w += wa * ha.w;
    }
    float4 b4 = *(const float4*)(bias + 4 * j);
    float rx = acc.x + b4.x; rx = (rx > 0.f) ? rx : expm1f(rx);
    float ry = acc.y + b4.y; ry = (ry > 0.f) ? ry : expm1f(ry);
    float rz = acc.z + b4.z; rz = (rz > 0.f) ? rz : expm1f(rz);
    float rw = acc.w + b4.w; rw = (rw > 0.f) ? rw : expm1f(rw);
    ushort4 o;
    o.x = f2bfu(rx); o.y = f2bfu(ry); o.z = f2bfu(rz); o.w = f2bfu(rw);
    *(ushort4*)(outb + (size_t)r * cHID + 4 * j) = o;
}

// ---------------- batched layer-2 agg + fused MLP head ----------------
__global__ void TemporalGAT_20005957665499_kernel(
        const unsigned short* __restrict__ hb, const float* __restrict__ es,
        const float* __restrict__ ed, const float* __restrict__ inv_arr,
        const int* __restrict__ offs, const int* __restrict__ csr,
        const float* __restrict__ bias,
        const float* __restrict__ lw1, const float* __restrict__ lb1,
        const float* __restrict__ lw2, const float* __restrict__ lb2,
        float* __restrict__ out) {
    __shared__ float lw1s[32 * 129];
    __shared__ float xs[8][128];
    __shared__ float lw2s[32];
    __shared__ float lb1s[32];
    int tid = threadIdx.x;
    for (int i = tid; i < 4096; i += 256)
        lw1s[(i >> 7) * 129 + (i & 127)] = lw1[i];
    if (tid < 32) { lw2s[tid] = lw2[tid]; lb1s[tid] = lb1[tid]; }

    int node = tid >> 5;
    int r = blockIdx.x * 8 + node;
    int j = tid & 31;
    int head = j >> 3;
    int n = r >> 3, t = r & 7;
    int u = r * cHEADS + head;
    int s0 = offs[n], s1 = offs[n + 1];
    float edn = ed[u], inv = inv_arr[u];
    int th = t * cHEADS + head;
    int tbase = t * cHID;

    float4 acc = make_float4(0.f, 0.f, 0.f, 0.f);
    int i = s0;
    for (; i + 1 < s1; i += 2) {
        int sa = csr[i], sb = csr[i + 1];
        float4 ha = bf4tof4(*(const ushort4*)(hb + (size_t)sa * (cT * cHID) + tbase + 4 * j));
        float4 hx = bf4tof4(*(const ushort4*)(hb + (size_t)sb * (cT * cHID) + tbase + 4 * j));
        float ea = es[sa * (cT * cHEADS) + th] + edn;
        float eb = es[sb * (cT * cHEADS) + th] + edn;
        ea = (ea >= 0.f) ? ea : cLEAKY * ea;
        eb = (eb >= 0.f) ? eb : cLEAKY * eb;
        float wa = __expf(ea) * inv;
        float wb = __expf(eb) * inv;
        acc.x += wa * ha.x + wb * hx.x;
        acc.y += wa * ha.y + wb * hx.y;
        acc.z += wa * ha.z + wb * hx.z;
        acc.w += wa * ha.w + wb * hx.w;
    }
    if (i < s1) {
        int sa = csr[i];
        float4 ha = bf4tof4(*(const ushort4*)(hb + (size_t)sa * (cT * cHID) + tbase + 4 * j));
        float ea = es[sa * (cT * cHEADS) + th] + edn;
        ea = (ea >= 0.f) ? ea : cLEAKY * ea;
        float wa = __expf(ea) * inv;
        acc.x += wa * ha.x; acc.y += wa * ha.y; acc.z += wa * ha.z; acc.w += wa * ha.w;
    }
    float4 b4 = *(const float4*)(bias + 4 * j);
    float4 rr;
    rr.x = acc.x + b4.x; rr.x = (rr.x > 0.f) ? rr.x : expm1f(rr.x);
    rr.y = acc.y + b4.y; rr.y = (rr.y > 0.f) ? rr.y : expm1f(rr.y);
    rr.z = acc.z + b4.z; rr.z = (rr.z > 0.f) ? rr.z : expm1f(rr.z);
    rr.w = acc.w + b4.w; rr.w = (rr.w > 0.f) ? rr.w : expm1f(rr.w);
    xs[node][4 * j + 0] = rr.x;
    xs[node][4 * j + 1] = rr.y;
    xs[node][4 * j + 2] = rr.z;
    xs[node][4 * j + 3] = rr.w;
    __syncthreads();

    const float* xrow = xs[node];
    const float* wrow = &lw1s[j * 129];
    float s = 0.f;
    #pragma unroll 8
    for (int k = 0; k < cHID; k++) s += xrow[k] * wrow[k];
    s += lb1s[j];
    s = fmaxf(s, 0.f);
    float v = s * lw2s[j];
    v += __shfl_xor(v, 16);
    v += __shfl_xor(v, 8);
    v += __shfl_xor(v, 4);
    v += __shfl_xor(v, 2);
    v += __shfl_xor(v, 1);
    if (j == 0) out[t * cN + n] = v + lb2[0];
}

// ---------------- launch ----------------
extern "C" void kernel_launch(void* const* d_in, const int* in_sizes, int n_in,
                              void* d_out, int out_size, void* d_ws, size_t ws_size,
                              hipStream_t stream) {
    const float* x   = (const float*)d_in[0];   // [N,T,64] fp32 == [r=(n,t)][64]
    const int*   ei  = (const int*)d_in[1];
    const float* W1  = (const float*)d_in[2];
    const float* as1 = (const float*)d_in[3];
    const float* ad1 = (const float*)d_in[4];
    const float* b1  = (const float*)d_in[5];
    const float* W2  = (const float*)d_in[6];
    const float* as2 = (const float*)d_in[7];
    const float* ad2 = (const float*)d_in[8];
    const float* b2  = (const float*)d_in[9];
    const float* lw1 = (const float*)d_in[10];
    const float* lb1 = (const float*)d_in[11];
    const float* lw2 = (const float*)d_in[12];
    const float* lb2 = (const float*)d_in[13];
    float* out = (float*)d_out;                 // [T,N,1] fp32
    (void)in_sizes; (void)n_in; (void)out_size; (void)ws_size;

    // workspace carve (~120 MB of 256 MB), 256B-aligned
    char* ws = (char*)d_ws;
    size_t o = 0;
    auto carveN = [&](size_t bytes) { void* p = ws + o; o += (bytes + 255) & ~(size_t)255; return p; };
    unsigned short* xb   = (unsigned short*)carveN((size_t)cR * cFIN * 2);    // 20.5 MB
    unsigned short* hb   = (unsigned short*)carveN((size_t)cR * cHID * 2);    // 41 MB
    unsigned short* xb2  = (unsigned short*)carveN((size_t)cR * cHID * 2);    // 41 MB
    unsigned short* W1b  = (unsigned short*)carveN((size_t)cHID * cFIN * 2);
    unsigned short* W2b  = (unsigned short*)carveN((size_t)cHID * cHID * 2);
    float* es_buf  = (float*)carveN((size_t)cR * cHEADS * 4);                 // 2.6 MB
    float* ed_buf  = (float*)carveN((size_t)cR * cHEADS * 4);
    float* inv_buf = (float*)carveN((size_t)cR * cHEADS * 4);
    int*   deg     = (int*)carveN((size_t)cN * 4);
    int*   offs    = (int*)carveN((size_t)(cN + 1) * 4);
    int*   cursor  = (int*)carveN((size_t)cN * 4);
    int*   csr     = (int*)carveN((size_t)cET * 4);

    // ---- conversions (x layout already row-major in r) ----
    cvt_kernel<<<(cR * cFIN + 255) / 256, 256, 0, stream>>>(x, xb, cR * cFIN);
    cvt_kernel<<<(cHID * cFIN + 255) / 256, 256, 0, stream>>>(W1, W1b, cHID * cFIN);
    cvt_kernel<<<(cHID * cHID + 255) / 256, 256, 0, stream>>>(W2, W2b, cHID * cHID);

    // ---- CSR build ----
    deg_init_kernel<<<(cN + 255) / 256, 256, 0, stream>>>(deg);
    deg_count_kernel<<<(cE + 255) / 256, 256, 0, stream>>>(ei, deg);
    scan_kernel<<<1, 256, 0, stream>>>(deg, offs);
    cursor_copy_kernel<<<(cN + 255) / 256, 256, 0, stream>>>(offs, cursor);
    scatter_kernel<<<(cET + 255) / 256, 256, 0, stream>>>(ei, cursor, csr);

    const int STAT_G = (cR * cHEADS + 255) / 256;   // 2500
    // ---- layer 1 (all T batched) ----
    gemm_mfma_kernel<cFIN><<<cR / 64, 256, 0, stream>>>(xb, W1b, as1, ad1, hb, es_buf, ed_buf);
    stats_kernel<<<STAT_G, 256, 0, stream>>>(es_buf, ed_buf, offs, csr, inv_buf);
    agg_kernel<<<cR / 8, 256, 0, stream>>>(hb, es_buf, ed_buf, inv_buf, offs, csr, b1, xb2);
    // ---- layer 2 (all T batched) + fused MLP ----
    gemm_mfma_kernel<cHID><<<cR / 64, 256, 0, stream>>>(xb2, W2b, as2, ad2, hb, es_buf, ed_buf);
    stats_kernel<<<STAT_G, 256, 0, stream>>>(es_buf, ed_buf, offs, csr, inv_buf);
    TemporalGAT_20005957665499_kernel<<<cR / 8, 256, 0, stream>>>(
        hb, es_buf, ed_buf, inv_buf, offs, csr, b2, lw1, lb1, lw2, lb2, out);
}

// Round 11
// 505.099 us; speedup vs baseline: 3.9466x; 1.1621x over previous
//
#include <hip/hip_runtime.h>

// ---------------- problem constants ----------------
constexpr int cN     = 20000;
constexpr int cT     = 8;
constexpr int cFIN   = 64;
constexpr int cHEADS = 4;
constexpr int cF     = 32;
constexpr int cHID   = 128;        // cHEADS * cF
constexpr int cE     = 320000;
constexpr int cET    = cE + cN;    // edges + self loops
constexpr int cR     = cN * cT;    // 160000 batched rows, r = n*8 + t
constexpr float cLEAKY = 0.2f;

typedef __attribute__((ext_vector_type(8))) short bf16x8;   // MFMA A/B frag
typedef __attribute__((ext_vector_type(4))) float f32x4;    // MFMA C/D frag

static __device__ __forceinline__ unsigned short f2bfu(float f) {
    unsigned int u;
    __builtin_memcpy(&u, &f, 4);
    u += 0x7FFFu + ((u >> 16) & 1u);
    return (unsigned short)(u >> 16);
}
static __device__ __forceinline__ float bfu2f(unsigned short b) {
    unsigned int u = ((unsigned int)b) << 16;
    float f;
    __builtin_memcpy(&f, &u, 4);
    return f;
}
static __device__ __forceinline__ float4 bf4tof4(ushort4 v) {
    return make_float4(bfu2f(v.x), bfu2f(v.y), bfu2f(v.z), bfu2f(v.w));
}

// ---------------- dtype conversion (flat) ----------------
__global__ void cvt_kernel(const float* s, unsigned short* d, int n) {
    int i = blockIdx.x * 256 + threadIdx.x;
    if (i < n) d[i] = f2bfu(s[i]);
}

// ---------------- CSR build ----------------
__global__ void deg_init_kernel(int* deg) {
    int n = blockIdx.x * blockDim.x + threadIdx.x;
    if (n < cN) deg[n] = 1;   // self loop
}
__global__ void deg_count_kernel(const int* ei, int* deg) {
    int e = blockIdx.x * blockDim.x + threadIdx.x;
    if (e < cE) atomicAdd(&deg[ei[cE + e]], 1);
}
__global__ void scan_kernel(const int* deg, int* offs) {
    __shared__ int lds[256];
    const int CH = 80;
    int tid  = threadIdx.x;
    int base = tid * CH;
    int tot = 0;
    for (int j = 0; j < CH; j++) {
        int idx = base + j;
        if (idx < cN) tot += deg[idx];
    }
    lds[tid] = tot;
    __syncthreads();
    for (int off = 1; off < 256; off <<= 1) {
        int v = (tid >= off) ? lds[tid - off] : 0;
        __syncthreads();
        lds[tid] += v;
        __syncthreads();
    }
    int run = lds[tid] - tot;
    for (int j = 0; j < CH; j++) {
        int idx = base + j;
        if (idx < cN) { offs[idx] = run; run += deg[idx]; }
    }
    if (tid == 255) offs[cN] = lds[255];
}
__global__ void cursor_copy_kernel(const int* offs, int* cur) {
    int n = blockIdx.x * blockDim.x + threadIdx.x;
    if (n < cN) cur[n] = offs[n];
}
__global__ void scatter_kernel(const int* ei, int* cur, int* csr) {
    int e = blockIdx.x * blockDim.x + threadIdx.x;
    if (e >= cET) return;
    int s, d;
    if (e < cE) { s = ei[e]; d = ei[cE + e]; }
    else        { s = e - cE; d = s; }
    int pos = atomicAdd(&cur[d], 1);
    csr[pos] = s;
}

// ---------------- batched MFMA GEMM + fused scores ----------------
// C[r,c] = sum_k A[r,k]*W[c,k] over all R=160000 rows (r=n*8+t).
// Output: hb bf16 [R,128] (coalesced via LDS) + es/ed fp32 [R*4].
template<int K>
__global__ __launch_bounds__(256) void gemm_mfma_kernel(
        const unsigned short* __restrict__ A, const unsigned short* __restrict__ W,
        const float* __restrict__ a_src, const float* __restrict__ a_dst,
        unsigned short* __restrict__ hb, float* __restrict__ es, float* __restrict__ ed) {
    __shared__ float hl[64][132];      // 33.8 KB
    int tid  = threadIdx.x;
    int wave = tid >> 6;
    int lane = tid & 63;
    int q    = lane >> 4;
    int mi   = lane & 15;
    int m0   = blockIdx.x * 64 + wave * 16;   // R % 64 == 0: no tail

    bf16x8 afrag[K / 32];
    #pragma unroll
    for (int s = 0; s < K / 32; s++)
        afrag[s] = *(const bf16x8*)(A + (size_t)(m0 + mi) * K + s * 32 + q * 8);

    f32x4 acc[8];
    #pragma unroll
    for (int ct = 0; ct < 8; ct++) acc[ct] = (f32x4){0.f, 0.f, 0.f, 0.f};
    #pragma unroll
    for (int ct = 0; ct < 8; ct++) {
        int c = ct * 16 + mi;
        #pragma unroll
        for (int s = 0; s < K / 32; s++) {
            bf16x8 bfrag = *(const bf16x8*)(W + (size_t)c * K + s * 32 + q * 8);
            acc[ct] = __builtin_amdgcn_mfma_f32_16x16x32_bf16(afrag[s], bfrag, acc[ct], 0, 0, 0);
        }
    }

    // stage fp32 tile in LDS
    #pragma unroll
    for (int ct = 0; ct < 8; ct++)
        #pragma unroll
        for (int r = 0; r < 4; r++)
            hl[wave * 16 + q * 4 + r][ct * 16 + mi] = acc[ct][r];
    __syncthreads();

    // scores: wave hd handles head hd for all 64 rows
    {
        int r2 = tid & 63;
        int hd = tid >> 6;
        int rg = blockIdx.x * 64 + r2;
        const float* hr = &hl[r2][hd * cF];
        const float* sa = a_src + hd * cF;
        const float* da = a_dst + hd * cF;
        float s1 = 0.f, s2 = 0.f;
        #pragma unroll 8
        for (int f = 0; f < cF; f++) {
            float hv = hr[f];
            s1 += hv * sa[f];
            s2 += hv * da[f];
        }
        es[rg * cHEADS + hd] = s1;
        ed[rg * cHEADS + hd] = s2;
    }

    // coalesced bf16 writeout of the 64x128 tile
    size_t base = (size_t)blockIdx.x * 64 * cHID;
    #pragma unroll
    for (int it = 0; it < 8; it++) {
        int g   = tid + it * 256;        // float4 group id, 2048 total
        int row = g >> 5;
        int c4  = (g & 31) * 4;
        float4 v = *(const float4*)&hl[row][c4];
        ushort4 o;
        o.x = f2bfu(v.x); o.y = f2bfu(v.y); o.z = f2bfu(v.z); o.w = f2bfu(v.w);
        *(ushort4*)(hb + base + (size_t)row * cHID + c4) = o;
    }
}

// ---------------- batched agg: gather + inline softmax denom + bias + ELU -> bf16 ----------------
// 32 lanes per row, 8 rows per block (block = one node, all 8 timesteps).
// Denominator accumulated in-loop (exp already computed); normalize at end.
__global__ void agg_kernel(const unsigned short* __restrict__ hb, const float* __restrict__ es,
                           const float* __restrict__ ed,
                           const int* __restrict__ offs, const int* __restrict__ csr,
                           const float* __restrict__ bias, unsigned short* __restrict__ outb) {
    int r = blockIdx.x * 8 + (threadIdx.x >> 5);
    int j = threadIdx.x & 31;
    int head = j >> 3;
    int n = r >> 3, t = r & 7;
    int u = r * cHEADS + head;
    int s0 = offs[n], s1 = offs[n + 1];
    float edn = ed[u];
    int th = t * cHEADS + head;
    int tbase = t * cHID;

    float4 acc = make_float4(0.f, 0.f, 0.f, 0.f);
    float den = 0.f;
    int i = s0;
    for (; i + 1 < s1; i += 2) {
        int sa = csr[i], sb = csr[i + 1];
        float4 ha = bf4tof4(*(const ushort4*)(hb + (size_t)sa * (cT * cHID) + tbase + 4 * j));
        float4 hx = bf4tof4(*(const ushort4*)(hb + (size_t)sb * (cT * cHID) + tbase + 4 * j));
        float ea = es[sa * (cT * cHEADS) + th] + edn;
        float eb = es[sb * (cT * cHEADS) + th] + edn;
        ea = (ea >= 0.f) ? ea : cLEAKY * ea;
        eb = (eb >= 0.f) ? eb : cLEAKY * eb;
        float wa = __expf(ea);
        float wb = __expf(eb);
        den += wa + wb;
        acc.x += wa * ha.x + wb * hx.x;
        acc.y += wa * ha.y + wb * hx.y;
        acc.z += wa * ha.z + wb * hx.z;
        acc.w += wa * ha.w + wb * hx.w;
    }
    if (i < s1) {
        int sa = csr[i];
        float4 ha = bf4tof4(*(const ushort4*)(hb + (size_t)sa * (cT * cHID) + tbase + 4 * j));
        float ea = es[sa * (cT * cHEADS) + th] + edn;
        ea = (ea >= 0.f) ? ea : cLEAKY * ea;
        float wa = __expf(ea);
        den += wa;
        acc.x += wa * ha.x; acc.y += wa * ha.y; acc.z += wa * ha.z; acc.w += wa * ha.w;
    }
    float inv = 1.f / (den + 1e-16f);
    float4 b4 = *(const float4*)(bias + 4 * j);
    float rx = acc.x * inv + b4.x; rx = (rx > 0.f) ? rx : expm1f(rx);
    float ry = acc.y * inv + b4.y; ry = (ry > 0.f) ? ry : expm1f(ry);
    float rz = acc.z * inv + b4.z; rz = (rz > 0.f) ? rz : expm1f(rz);
    float rw = acc.w * inv + b4.w; rw = (rw > 0.f) ? rw : expm1f(rw);
    ushort4 o;
    o.x = f2bfu(rx); o.y = f2bfu(ry); o.z = f2bfu(rz); o.w = f2bfu(rw);
    *(ushort4*)(outb + (size_t)r * cHID + 4 * j) = o;
}

// ---------------- MFMA MLP head: relu(X@lw1.T+lb1)@lw2.T + lb2 -> out[t,n] ----------------
// X [R,128] bf16; lw1b [32,128] bf16. 64 rows/block, 4 waves x 16 rows.
// C layout: col=lane&15, row=quad*4+reg; row-sum via shfl_xor 1/2/4/8 within 16 lanes.
__global__ __launch_bounds__(256) void TemporalGAT_20005957665499_kernel(
        const unsigned short* __restrict__ X, const unsigned short* __restrict__ lw1b,
        const float* __restrict__ lb1, const float* __restrict__ lw2,
        const float* __restrict__ lb2, float* __restrict__ out) {
    int tid  = threadIdx.x;
    int wave = tid >> 6;
    int lane = tid & 63;
    int q    = lane >> 4;
    int mi   = lane & 15;
    int m0   = blockIdx.x * 64 + wave * 16;

    bf16x8 afrag[4];
    #pragma unroll
    for (int s = 0; s < 4; s++)
        afrag[s] = *(const bf16x8*)(X + (size_t)(m0 + mi) * cHID + s * 32 + q * 8);

    f32x4 acc[2];
    acc[0] = (f32x4){0.f, 0.f, 0.f, 0.f};
    acc[1] = (f32x4){0.f, 0.f, 0.f, 0.f};
    #pragma unroll
    for (int ct = 0; ct < 2; ct++) {
        int c = ct * 16 + mi;
        #pragma unroll
        for (int s = 0; s < 4; s++) {
            bf16x8 bfrag = *(const bf16x8*)(lw1b + (size_t)c * cHID + s * 32 + q * 8);
            acc[ct] = __builtin_amdgcn_mfma_f32_16x16x32_bf16(afrag[s], bfrag, acc[ct], 0, 0, 0);
        }
    }

    float lb1a = lb1[mi], lb1b_ = lb1[16 + mi];
    float lw2a = lw2[mi], lw2b_ = lw2[16 + mi];
    float l2 = lb2[0];
    #pragma unroll
    for (int r = 0; r < 4; r++) {
        float va = acc[0][r] + lb1a; va = fmaxf(va, 0.f);
        float vb = acc[1][r] + lb1b_; vb = fmaxf(vb, 0.f);
        float v = va * lw2a + vb * lw2b_;
        v += __shfl_xor(v, 1);
        v += __shfl_xor(v, 2);
        v += __shfl_xor(v, 4);
        v += __shfl_xor(v, 8);
        if (mi == 0) {
            int row = m0 + q * 4 + r;
            int n = row >> 3, t = row & 7;
            out[t * cN + n] = v + l2;
        }
    }
}

// ---------------- launch ----------------
extern "C" void kernel_launch(void* const* d_in, const int* in_sizes, int n_in,
                              void* d_out, int out_size, void* d_ws, size_t ws_size,
                              hipStream_t stream) {
    const float* x   = (const float*)d_in[0];   // [N,T,64] fp32 == [r=(n,t)][64]
    const int*   ei  = (const int*)d_in[1];
    const float* W1  = (const float*)d_in[2];
    const float* as1 = (const float*)d_in[3];
    const float* ad1 = (const float*)d_in[4];
    const float* b1  = (const float*)d_in[5];
    const float* W2  = (const float*)d_in[6];
    const float* as2 = (const float*)d_in[7];
    const float* ad2 = (const float*)d_in[8];
    const float* b2  = (const float*)d_in[9];
    const float* lw1 = (const float*)d_in[10];
    const float* lb1 = (const float*)d_in[11];
    const float* lw2 = (const float*)d_in[12];
    const float* lb2 = (const float*)d_in[13];
    float* out = (float*)d_out;                 // [T,N,1] fp32
    (void)in_sizes; (void)n_in; (void)out_size; (void)ws_size;

    // workspace carve (~150 MB of 256 MB), 256B-aligned
    char* ws = (char*)d_ws;
    size_t o = 0;
    auto carveN = [&](size_t bytes) { void* p = ws + o; o += (bytes + 255) & ~(size_t)255; return p; };
    unsigned short* xb   = (unsigned short*)carveN((size_t)cR * cFIN * 2);    // 20.5 MB
    unsigned short* hb   = (unsigned short*)carveN((size_t)cR * cHID * 2);    // 41 MB
    unsigned short* xb2  = (unsigned short*)carveN((size_t)cR * cHID * 2);    // 41 MB
    unsigned short* xb3  = (unsigned short*)carveN((size_t)cR * cHID * 2);    // 41 MB (MLP input)
    unsigned short* W1b  = (unsigned short*)carveN((size_t)cHID * cFIN * 2);
    unsigned short* W2b  = (unsigned short*)carveN((size_t)cHID * cHID * 2);
    unsigned short* lw1b = (unsigned short*)carveN((size_t)cF * cHID * 2);
    float* es_buf  = (float*)carveN((size_t)cR * cHEADS * 4);                 // 2.6 MB
    float* ed_buf  = (float*)carveN((size_t)cR * cHEADS * 4);
    int*   deg     = (int*)carveN((size_t)cN * 4);
    int*   offs    = (int*)carveN((size_t)(cN + 1) * 4);
    int*   cursor  = (int*)carveN((size_t)cN * 4);
    int*   csr     = (int*)carveN((size_t)cET * 4);

    // ---- conversions ----
    cvt_kernel<<<(cR * cFIN + 255) / 256, 256, 0, stream>>>(x, xb, cR * cFIN);
    cvt_kernel<<<(cHID * cFIN + 255) / 256, 256, 0, stream>>>(W1, W1b, cHID * cFIN);
    cvt_kernel<<<(cHID * cHID + 255) / 256, 256, 0, stream>>>(W2, W2b, cHID * cHID);
    cvt_kernel<<<(cF * cHID + 255) / 256, 256, 0, stream>>>(lw1, lw1b, cF * cHID);

    // ---- CSR build ----
    deg_init_kernel<<<(cN + 255) / 256, 256, 0, stream>>>(deg);
    deg_count_kernel<<<(cE + 255) / 256, 256, 0, stream>>>(ei, deg);
    scan_kernel<<<1, 256, 0, stream>>>(deg, offs);
    cursor_copy_kernel<<<(cN + 255) / 256, 256, 0, stream>>>(offs, cursor);
    scatter_kernel<<<(cET + 255) / 256, 256, 0, stream>>>(ei, cursor, csr);

    // ---- layer 1 (all T batched) ----
    gemm_mfma_kernel<cFIN><<<cR / 64, 256, 0, stream>>>(xb, W1b, as1, ad1, hb, es_buf, ed_buf);
    agg_kernel<<<cN, 256, 0, stream>>>(hb, es_buf, ed_buf, offs, csr, b1, xb2);
    // ---- layer 2 (all T batched) ----
    gemm_mfma_kernel<cHID><<<cR / 64, 256, 0, stream>>>(xb2, W2b, as2, ad2, hb, es_buf, ed_buf);
    agg_kernel<<<cN, 256, 0, stream>>>(hb, es_buf, ed_buf, offs, csr, b2, xb3);
    // ---- MFMA MLP head -> out ----
    TemporalGAT_20005957665499_kernel<<<cR / 64, 256, 0, stream>>>(xb3, lw1b, lb1, lw2, lb2, out);
}

// Round 12
// 478.701 us; speedup vs baseline: 4.1642x; 1.0551x over previous
//
#include <hip/hip_runtime.h>

// ---------------- problem constants ----------------
constexpr int cN     = 20000;
constexpr int cT     = 8;
constexpr int cFIN   = 64;
constexpr int cHEADS = 4;
constexpr int cF     = 32;
constexpr int cHID   = 128;        // cHEADS * cF
constexpr int cE     = 320000;
constexpr int cET    = cE + cN;    // edges + self loops
constexpr int cR     = cN * cT;    // 160000 batched rows, rho = t*N + n (t-major!)
constexpr float cLEAKY = 0.2f;

typedef __attribute__((ext_vector_type(8))) short bf16x8;   // MFMA A/B frag
typedef __attribute__((ext_vector_type(4))) float f32x4;    // MFMA C/D frag

static __device__ __forceinline__ unsigned short f2bfu(float f) {
    unsigned int u;
    __builtin_memcpy(&u, &f, 4);
    u += 0x7FFFu + ((u >> 16) & 1u);
    return (unsigned short)(u >> 16);
}
// unpack bf16 pair (packed in uint) -> two floats (1 SHL + 1 AND)
static __device__ __forceinline__ void unpack2(unsigned int v, float& lo, float& hi) {
    unsigned int ul = v << 16, uh = v & 0xFFFF0000u;
    __builtin_memcpy(&lo, &ul, 4);
    __builtin_memcpy(&hi, &uh, 4);
}
// pack two floats -> bf16 pair (RNE)
static __device__ __forceinline__ unsigned int pack2(float lo, float hi) {
    unsigned int ul, uh;
    __builtin_memcpy(&ul, &lo, 4);
    __builtin_memcpy(&uh, &hi, 4);
    ul += 0x7FFFu + ((ul >> 16) & 1u);
    uh += 0x7FFFu + ((uh >> 16) & 1u);
    return (ul >> 16) | (uh & 0xFFFF0000u);
}

// ---------------- conversions ----------------
// x [N,T,64] fp32 -> xb [rho=(t,n)][64] bf16 (t-major transpose)
__global__ void cvt_x_kernel(const float* x, unsigned short* xb) {
    int id = blockIdx.x * 256 + threadIdx.x;   // n*64 + k
    int t  = blockIdx.y;
    int n  = id >> 6, k = id & 63;
    xb[(size_t)t * cN * cFIN + id] = f2bfu(x[(size_t)n * (cT * cFIN) + t * cFIN + k]);
}
// all three weight matrices in one dispatch
__global__ void cvt_w_kernel(const float* W1, const float* W2, const float* lw1,
                             unsigned short* W1b, unsigned short* W2b, unsigned short* lw1b) {
    int i = blockIdx.x * 256 + threadIdx.x;
    if (i < cHID * cFIN)                      W1b[i] = f2bfu(W1[i]);
    else if (i < cHID * cFIN + cHID * cHID)   W2b[i - cHID * cFIN] = f2bfu(W2[i - cHID * cFIN]);
    else if (i < cHID * cFIN + cHID * cHID + cF * cHID)
        lw1b[i - cHID * cFIN - cHID * cHID] = f2bfu(lw1[i - cHID * cFIN - cHID * cHID]);
}

// ---------------- CSR build ----------------
__global__ void deg_init_kernel(int* deg) {
    int n = blockIdx.x * blockDim.x + threadIdx.x;
    if (n < cN) deg[n] = 1;   // self loop
}
__global__ void deg_count_kernel(const int* ei, int* deg) {
    int e = blockIdx.x * blockDim.x + threadIdx.x;
    if (e < cE) atomicAdd(&deg[ei[cE + e]], 1);
}
__global__ void scan_kernel(const int* deg, int* offs, int* cur) {
    __shared__ int lds[256];
    const int CH = 80;
    int tid  = threadIdx.x;
    int base = tid * CH;
    int tot = 0;
    for (int j = 0; j < CH; j++) {
        int idx = base + j;
        if (idx < cN) tot += deg[idx];
    }
    lds[tid] = tot;
    __syncthreads();
    for (int off = 1; off < 256; off <<= 1) {
        int v = (tid >= off) ? lds[tid - off] : 0;
        __syncthreads();
        lds[tid] += v;
        __syncthreads();
    }
    int run = lds[tid] - tot;
    for (int j = 0; j < CH; j++) {
        int idx = base + j;
        if (idx < cN) { offs[idx] = run; cur[idx] = run; run += deg[idx]; }
    }
    if (tid == 255) offs[cN] = lds[255];
}
__global__ void scatter_kernel(const int* ei, int* cur, int* csr) {
    int e = blockIdx.x * blockDim.x + threadIdx.x;
    if (e >= cET) return;
    int s, d;
    if (e < cE) { s = ei[e]; d = ei[cE + e]; }
    else        { s = e - cE; d = s; }
    int pos = atomicAdd(&cur[d], 1);
    csr[pos] = s;
}

// ---------------- batched MFMA GEMM + fused scores (rows = rho, t-major) ----------------
// C[rho,c] = sum_k A[rho,k]*W[c,k]; out: hb bf16 [R,128] + es/ed fp32 [R*4].
template<int K>
__global__ __launch_bounds__(256) void gemm_mfma_kernel(
        const unsigned short* __restrict__ A, const unsigned short* __restrict__ W,
        const float* __restrict__ a_src, const float* __restrict__ a_dst,
        unsigned short* __restrict__ hb, float* __restrict__ es, float* __restrict__ ed) {
    __shared__ float hl[64][132];      // 33.8 KB
    int tid  = threadIdx.x;
    int wave = tid >> 6;
    int lane = tid & 63;
    int q    = lane >> 4;
    int mi   = lane & 15;
    int m0   = blockIdx.x * 64 + wave * 16;   // R % 64 == 0: no tail

    bf16x8 afrag[K / 32];
    #pragma unroll
    for (int s = 0; s < K / 32; s++)
        afrag[s] = *(const bf16x8*)(A + (size_t)(m0 + mi) * K + s * 32 + q * 8);

    f32x4 acc[8];
    #pragma unroll
    for (int ct = 0; ct < 8; ct++) acc[ct] = (f32x4){0.f, 0.f, 0.f, 0.f};
    #pragma unroll
    for (int ct = 0; ct < 8; ct++) {
        int c = ct * 16 + mi;
        #pragma unroll
        for (int s = 0; s < K / 32; s++) {
            bf16x8 bfrag = *(const bf16x8*)(W + (size_t)c * K + s * 32 + q * 8);
            acc[ct] = __builtin_amdgcn_mfma_f32_16x16x32_bf16(afrag[s], bfrag, acc[ct], 0, 0, 0);
        }
    }

    // stage fp32 tile in LDS
    #pragma unroll
    for (int ct = 0; ct < 8; ct++)
        #pragma unroll
        for (int r = 0; r < 4; r++)
            hl[wave * 16 + q * 4 + r][ct * 16 + mi] = acc[ct][r];
    __syncthreads();

    // scores: wave hd handles head hd for all 64 rows
    {
        int r2 = tid & 63;
        int hd = tid >> 6;
        int rg = blockIdx.x * 64 + r2;
        const float* hr = &hl[r2][hd * cF];
        const float* sa = a_src + hd * cF;
        const float* da = a_dst + hd * cF;
        float s1 = 0.f, s2 = 0.f;
        #pragma unroll 8
        for (int f = 0; f < cF; f++) {
            float hv = hr[f];
            s1 += hv * sa[f];
            s2 += hv * da[f];
        }
        es[rg * cHEADS + hd] = s1;
        ed[rg * cHEADS + hd] = s2;
    }

    // coalesced bf16 writeout of the 64x128 tile
    size_t base = (size_t)blockIdx.x * 64 * cHID;
    #pragma unroll
    for (int it = 0; it < 8; it++) {
        int g   = tid + it * 256;        // float4 group id, 2048 total
        int row = g >> 5;
        int c4  = (g & 31) * 4;
        float4 v = *(const float4*)&hl[row][c4];
        unsigned int p0 = pack2(v.x, v.y), p1 = pack2(v.z, v.w);
        *(uint2*)(hb + base + (size_t)row * cHID + c4) = make_uint2(p0, p1);
    }
}

// ---------------- t-plane agg: gather + inline softmax + bias + ELU -> bf16 ----------------
// grid (N/16, T): block = 16 nodes of one t-plane (plane = 2.56MB hb + 0.32MB es: L2-resident).
// 16 lanes per row, 16B (8 bf16) per lane.
__global__ void agg_kernel(const unsigned short* __restrict__ hb, const float* __restrict__ es,
                           const float* __restrict__ ed,
                           const int* __restrict__ offs, const int* __restrict__ csr,
                           const float* __restrict__ bias, unsigned short* __restrict__ outb) {
    int t    = blockIdx.y;
    int lrow = threadIdx.x >> 4;
    int n    = blockIdx.x * 16 + lrow;
    int j    = threadIdx.x & 15;        // features 8j..8j+7
    int head = j >> 2;
    size_t plane = (size_t)t * cN;
    int rho = t * cN + n;
    int s0 = offs[n], s1 = offs[n + 1];
    float edn = ed[(size_t)rho * cHEADS + head];
    const unsigned short* hp = hb + plane * cHID;
    const float* ep = es + plane * cHEADS;

    float acc[8] = {};
    float den = 0.f;
    int i = s0;
    for (; i + 1 < s1; i += 2) {
        int sa = csr[i], sb = csr[i + 1];
        uint4 ra = *(const uint4*)(hp + (size_t)sa * cHID + 8 * j);
        uint4 rb = *(const uint4*)(hp + (size_t)sb * cHID + 8 * j);
        float ea = ep[sa * cHEADS + head] + edn;
        float eb = ep[sb * cHEADS + head] + edn;
        ea = (ea >= 0.f) ? ea : cLEAKY * ea;
        eb = (eb >= 0.f) ? eb : cLEAKY * eb;
        float wa = __expf(ea), wb = __expf(eb);
        den += wa + wb;
        float l0, h0, l1, h1;
        unpack2(ra.x, l0, h0); acc[0] += wa * l0; acc[1] += wa * h0;
        unpack2(ra.y, l1, h1); acc[2] += wa * l1; acc[3] += wa * h1;
        unpack2(ra.z, l0, h0); acc[4] += wa * l0; acc[5] += wa * h0;
        unpack2(ra.w, l1, h1); acc[6] += wa * l1; acc[7] += wa * h1;
        unpack2(rb.x, l0, h0); acc[0] += wb * l0; acc[1] += wb * h0;
        unpack2(rb.y, l1, h1); acc[2] += wb * l1; acc[3] += wb * h1;
        unpack2(rb.z, l0, h0); acc[4] += wb * l0; acc[5] += wb * h0;
        unpack2(rb.w, l1, h1); acc[6] += wb * l1; acc[7] += wb * h1;
    }
    if (i < s1) {
        int sa = csr[i];
        uint4 ra = *(const uint4*)(hp + (size_t)sa * cHID + 8 * j);
        float ea = ep[sa * cHEADS + head] + edn;
        ea = (ea >= 0.f) ? ea : cLEAKY * ea;
        float wa = __expf(ea);
        den += wa;
        float l0, h0;
        unpack2(ra.x, l0, h0); acc[0] += wa * l0; acc[1] += wa * h0;
        unpack2(ra.y, l0, h0); acc[2] += wa * l0; acc[3] += wa * h0;
        unpack2(ra.z, l0, h0); acc[4] += wa * l0; acc[5] += wa * h0;
        unpack2(ra.w, l0, h0); acc[6] += wa * l0; acc[7] += wa * h0;
    }
    float inv = 1.f / (den + 1e-16f);
    float4 b0 = *(const float4*)(bias + 8 * j);
    float4 b1 = *(const float4*)(bias + 8 * j + 4);
    float r0 = acc[0] * inv + b0.x; r0 = (r0 > 0.f) ? r0 : expm1f(r0);
    float r1 = acc[1] * inv + b0.y; r1 = (r1 > 0.f) ? r1 : expm1f(r1);
    float r2 = acc[2] * inv + b0.z; r2 = (r2 > 0.f) ? r2 : expm1f(r2);
    float r3 = acc[3] * inv + b0.w; r3 = (r3 > 0.f) ? r3 : expm1f(r3);
    float r4 = acc[4] * inv + b1.x; r4 = (r4 > 0.f) ? r4 : expm1f(r4);
    float r5 = acc[5] * inv + b1.y; r5 = (r5 > 0.f) ? r5 : expm1f(r5);
    float r6 = acc[6] * inv + b1.z; r6 = (r6 > 0.f) ? r6 : expm1f(r6);
    float r7 = acc[7] * inv + b1.w; r7 = (r7 > 0.f) ? r7 : expm1f(r7);
    uint4 o;
    o.x = pack2(r0, r1); o.y = pack2(r2, r3); o.z = pack2(r4, r5); o.w = pack2(r6, r7);
    *(uint4*)(outb + (size_t)rho * cHID + 8 * j) = o;
}

// ---------------- MFMA MLP head: relu(X@lw1.T+lb1)@lw2.T + lb2 -> out[rho] ----------------
__global__ __launch_bounds__(256) void TemporalGAT_20005957665499_kernel(
        const unsigned short* __restrict__ X, const unsigned short* __restrict__ lw1b,
        const float* __restrict__ lb1, const float* __restrict__ lw2,
        const float* __restrict__ lb2, float* __restrict__ out) {
    int tid  = threadIdx.x;
    int wave = tid >> 6;
    int lane = tid & 63;
    int q    = lane >> 4;
    int mi   = lane & 15;
    int m0   = blockIdx.x * 64 + wave * 16;

    bf16x8 afrag[4];
    #pragma unroll
    for (int s = 0; s < 4; s++)
        afrag[s] = *(const bf16x8*)(X + (size_t)(m0 + mi) * cHID + s * 32 + q * 8);

    f32x4 acc[2];
    acc[0] = (f32x4){0.f, 0.f, 0.f, 0.f};
    acc[1] = (f32x4){0.f, 0.f, 0.f, 0.f};
    #pragma unroll
    for (int ct = 0; ct < 2; ct++) {
        int c = ct * 16 + mi;
        #pragma unroll
        for (int s = 0; s < 4; s++) {
            bf16x8 bfrag = *(const bf16x8*)(lw1b + (size_t)c * cHID + s * 32 + q * 8);
            acc[ct] = __builtin_amdgcn_mfma_f32_16x16x32_bf16(afrag[s], bfrag, acc[ct], 0, 0, 0);
        }
    }

    float lb1a = lb1[mi], lb1b_ = lb1[16 + mi];
    float lw2a = lw2[mi], lw2b_ = lw2[16 + mi];
    float l2 = lb2[0];
    #pragma unroll
    for (int r = 0; r < 4; r++) {
        float va = acc[0][r] + lb1a; va = fmaxf(va, 0.f);
        float vb = acc[1][r] + lb1b_; vb = fmaxf(vb, 0.f);
        float v = va * lw2a + vb * lw2b_;
        v += __shfl_xor(v, 1);
        v += __shfl_xor(v, 2);
        v += __shfl_xor(v, 4);
        v += __shfl_xor(v, 8);
        if (mi == 0) out[m0 + q * 4 + r] = v + l2;   // rho-major == [T,N] output layout
    }
}

// ---------------- launch ----------------
extern "C" void kernel_launch(void* const* d_in, const int* in_sizes, int n_in,
                              void* d_out, int out_size, void* d_ws, size_t ws_size,
                              hipStream_t stream) {
    const float* x   = (const float*)d_in[0];   // [N,T,64] fp32
    const int*   ei  = (const int*)d_in[1];
    const float* W1  = (const float*)d_in[2];
    const float* as1 = (const float*)d_in[3];
    const float* ad1 = (const float*)d_in[4];
    const float* b1  = (const float*)d_in[5];
    const float* W2  = (const float*)d_in[6];
    const float* as2 = (const float*)d_in[7];
    const float* ad2 = (const float*)d_in[8];
    const float* b2  = (const float*)d_in[9];
    const float* lw1 = (const float*)d_in[10];
    const float* lb1 = (const float*)d_in[11];
    const float* lw2 = (const float*)d_in[12];
    const float* lb2 = (const float*)d_in[13];
    float* out = (float*)d_out;                 // [T,N,1] fp32 == rho-major
    (void)in_sizes; (void)n_in; (void)out_size; (void)ws_size;

    // workspace carve (~150 MB of 256 MB), 256B-aligned
    char* ws = (char*)d_ws;
    size_t o = 0;
    auto carveN = [&](size_t bytes) { void* p = ws + o; o += (bytes + 255) & ~(size_t)255; return p; };
    unsigned short* xb   = (unsigned short*)carveN((size_t)cR * cFIN * 2);    // 20.5 MB
    unsigned short* hb   = (unsigned short*)carveN((size_t)cR * cHID * 2);    // 41 MB
    unsigned short* xb2  = (unsigned short*)carveN((size_t)cR * cHID * 2);    // 41 MB
    unsigned short* xb3  = (unsigned short*)carveN((size_t)cR * cHID * 2);    // 41 MB
    unsigned short* W1b  = (unsigned short*)carveN((size_t)cHID * cFIN * 2);
    unsigned short* W2b  = (unsigned short*)carveN((size_t)cHID * cHID * 2);
    unsigned short* lw1b = (unsigned short*)carveN((size_t)cF * cHID * 2);
    float* es_buf  = (float*)carveN((size_t)cR * cHEADS * 4);                 // 2.6 MB
    float* ed_buf  = (float*)carveN((size_t)cR * cHEADS * 4);
    int*   deg     = (int*)carveN((size_t)cN * 4);
    int*   offs    = (int*)carveN((size_t)(cN + 1) * 4);
    int*   cursor  = (int*)carveN((size_t)cN * 4);
    int*   csr     = (int*)carveN((size_t)cET * 4);

    // ---- conversions ----
    cvt_x_kernel<<<dim3(cN * cFIN / 256, cT), 256, 0, stream>>>(x, xb);
    cvt_w_kernel<<<(cHID * cFIN + cHID * cHID + cF * cHID + 255) / 256, 256, 0, stream>>>(
        W1, W2, lw1, W1b, W2b, lw1b);

    // ---- CSR build ----
    deg_init_kernel<<<(cN + 255) / 256, 256, 0, stream>>>(deg);
    deg_count_kernel<<<(cE + 255) / 256, 256, 0, stream>>>(ei, deg);
    scan_kernel<<<1, 256, 0, stream>>>(deg, offs, cursor);
    scatter_kernel<<<(cET + 255) / 256, 256, 0, stream>>>(ei, cursor, csr);

    // ---- layer 1 ----
    gemm_mfma_kernel<cFIN><<<cR / 64, 256, 0, stream>>>(xb, W1b, as1, ad1, hb, es_buf, ed_buf);
    agg_kernel<<<dim3(cN / 16, cT), 256, 0, stream>>>(hb, es_buf, ed_buf, offs, csr, b1, xb2);
    // ---- layer 2 ----
    gemm_mfma_kernel<cHID><<<cR / 64, 256, 0, stream>>>(xb2, W2b, as2, ad2, hb, es_buf, ed_buf);
    agg_kernel<<<dim3(cN / 16, cT), 256, 0, stream>>>(hb, es_buf, ed_buf, offs, csr, b2, xb3);
    // ---- MFMA MLP head -> out ----
    TemporalGAT_20005957665499_kernel<<<cR / 64, 256, 0, stream>>>(xb3, lw1b, lb1, lw2, lb2, out);
}